// Round 1
// baseline (647.348 us; speedup 1.0000x reference)
//
#include <hip/hip_runtime.h>
#include <math.h>

#define DEV static __device__ __forceinline__

struct C2 { float r, i; };

// DPP quad-perm helpers (all group-of-4 lane traffic; full VALU rate, no LDS)
template<int CTRL>
DEV float qperm(float x) {
    return __int_as_float(__builtin_amdgcn_mov_dpp(__float_as_int(x), CTRL, 0xF, 0xF, true));
}
DEV float lx1(float v) { return qperm<0xB1>(v); } // xor lane bit0: perm [1,0,3,2]
DEV float lx2(float v) { return qperm<0x4E>(v); } // xor lane bit1: perm [2,3,0,1]
DEV float l13(float v) { return qperm<0x6C>(v); } // lanes 1<->3:   perm [0,3,2,1]

// General 2x2 complex unitary on a local qubit pair (a: bit=0 amp, b: bit=1 amp)
DEV void rot_pair(C2& a, C2& b, C2 u00, C2 u01, C2 u10, C2 u11) {
    float nar = u00.r*a.r - u00.i*a.i + u01.r*b.r - u01.i*b.i;
    float nai = u00.r*a.i + u00.i*a.r + u01.r*b.i + u01.i*b.r;
    float nbr = u10.r*a.r - u10.i*a.i + u11.r*b.r - u11.i*b.i;
    float nbi = u10.r*a.i + u10.i*a.r + u11.r*b.i + u11.i*b.r;
    a.r = nar; a.i = nai; b.r = nbr; b.i = nbi;
}

// Unitary on a lane-mapped qubit: new = alpha*own + beta*partner (coeffs pre-selected per thread)
template<int CTRL>
DEV void rot_lane(C2 a[4], C2 al, C2 be) {
#pragma unroll
    for (int m = 0; m < 4; ++m) {
        float pr = qperm<CTRL>(a[m].r);
        float pi = qperm<CTRL>(a[m].i);
        float nr = al.r*a[m].r - al.i*a[m].i + be.r*pr - be.i*pi;
        float ni = al.r*a[m].i + al.i*a[m].r + be.r*pi + be.i*pr;
        a[m].r = nr; a[m].i = ni;
    }
}

struct LayerC {
    C2 m0[4];          // qubit0 Rot matrix {u00,u01,u10,u11}
    C2 m1[4];          // qubit1 Rot matrix
    C2 a2, b2, a3, b3; // pre-selected lane-gate coefficients for qubits 2,3
};

// One StronglyEntangling layer: Rot on q0..q3, then CNOT ring (0,1)(1,2)(2,3)(3,0)
DEV void apply_layer(C2 a[4], const LayerC& L, bool f3) {
    rot_pair(a[0], a[1], L.m0[0], L.m0[1], L.m0[2], L.m0[3]);
    rot_pair(a[2], a[3], L.m0[0], L.m0[1], L.m0[2], L.m0[3]);
    rot_pair(a[0], a[2], L.m1[0], L.m1[1], L.m1[2], L.m1[3]);
    rot_pair(a[1], a[3], L.m1[0], L.m1[1], L.m1[2], L.m1[3]);
    rot_lane<0xB1>(a, L.a2, L.b2);
    rot_lane<0x4E>(a, L.a3, L.b3);
    // CNOT(0,1): local relabel — swap a[1] <-> a[3]
    { C2 t = a[1]; a[1] = a[3]; a[3] = t; }
    // CNOT(1,2): amps with b1=1 (m=2,3) exchange across lane-xor-1
    a[2].r = lx1(a[2].r); a[2].i = lx1(a[2].i);
    a[3].r = lx1(a[3].r); a[3].i = lx1(a[3].i);
    // CNOT(2,3): lane permutation 1<->3
#pragma unroll
    for (int m = 0; m < 4; ++m) { a[m].r = l13(a[m].r); a[m].i = l13(a[m].i); }
    // CNOT(3,0): lanes with b3=1 swap bit0 locally (thread-uniform select)
#pragma unroll
    for (int m = 0; m < 4; m += 2) {
        float t0r = f3 ? a[m+1].r : a[m].r;
        float t0i = f3 ? a[m+1].i : a[m].i;
        float t1r = f3 ? a[m].r   : a[m+1].r;
        float t1i = f3 ? a[m].i   : a[m+1].i;
        a[m].r = t0r; a[m].i = t0i; a[m+1].r = t1r; a[m+1].i = t1i;
    }
}

// theta/2 for the 4 local amps given the 7 embedding angles (IQP diag phase,
// CNOT-RZ-CNOT folded to ZZ sign products). s2f/s3f = (1-2*lane_bit).
DEV void diag_angles(const float ang[7], float s2f, float s3f, float th[4]) {
    float L_ = s2f*ang[2] + s3f*ang[3] + (s2f*s3f)*ang[6];
    float u  = s2f*ang[5];
    float Pp = u + L_, Qq = L_ - u;
    th[0] = 0.5f*( ang[0] + ang[1] + ang[4] + Pp);
    th[1] = 0.5f*(-ang[0] + ang[1] - ang[4] + Pp);
    th[2] = 0.5f*( ang[0] - ang[1] - ang[4] + Qq);
    th[3] = 0.5f*(-ang[0] - ang[1] + ang[4] + Qq);
}

// feature_map applied to |0000>: amp = 0.25 * e^{-i theta/2}
DEV void fm_from_zero(C2 a[4], const float ang[7], float s2f, float s3f) {
    float th[4];
    diag_angles(ang, s2f, s3f, th);
#pragma unroll
    for (int m = 0; m < 4; ++m) {
        float s, c; __sincosf(th[m], &s, &c);
        a[m].r = 0.25f*c; a[m].i = -0.25f*s;
    }
}

// feature_map on a live state: H^{x4} (scale folded) then diag phase
DEV void fm_h4_diag(C2 a[4], const float ang[7], float s2f, float s3f) {
    { // H on q0: pairs (0,1),(2,3)
        C2 n0 = {a[0].r+a[1].r, a[0].i+a[1].i}, n1 = {a[0].r-a[1].r, a[0].i-a[1].i};
        C2 n2 = {a[2].r+a[3].r, a[2].i+a[3].i}, n3 = {a[2].r-a[3].r, a[2].i-a[3].i};
        a[0]=n0; a[1]=n1; a[2]=n2; a[3]=n3;
    }
    { // H on q1: pairs (0,2),(1,3)
        C2 n0 = {a[0].r+a[2].r, a[0].i+a[2].i}, n2 = {a[0].r-a[2].r, a[0].i-a[2].i};
        C2 n1 = {a[1].r+a[3].r, a[1].i+a[3].i}, n3 = {a[1].r-a[3].r, a[1].i-a[3].i};
        a[0]=n0; a[1]=n1; a[2]=n2; a[3]=n3;
    }
#pragma unroll
    for (int m = 0; m < 4; ++m) { // H on q2 (lane bit0): new = partner + s*own
        float pr = lx1(a[m].r), pi = lx1(a[m].i);
        a[m].r = pr + s2f*a[m].r;
        a[m].i = pi + s2f*a[m].i;
    }
#pragma unroll
    for (int m = 0; m < 4; ++m) { // H on q3 (lane bit1)
        float pr = lx2(a[m].r), pi = lx2(a[m].i);
        a[m].r = pr + s3f*a[m].r;
        a[m].i = pi + s3f*a[m].i;
    }
    float th[4];
    diag_angles(ang, s2f, s3f, th);
#pragma unroll
    for (int m = 0; m < 4; ++m) { // amp *= 0.25*(c - i s)  (0.25 = folded H scale)
        float s, c; __sincosf(th[m], &s, &c);
        c *= 0.25f; s *= 0.25f;
        float nr = a[m].r*c + a[m].i*s;
        float ni = a[m].i*c - a[m].r*s;
        a[m].r = nr; a[m].i = ni;
    }
}

__global__ __launch_bounds__(256, 1)
void qrnn_kernel(const float* __restrict__ inputs, const float* __restrict__ initial_t,
                 const float* __restrict__ p1, const float* __restrict__ p2,
                 const float* __restrict__ kbw, const float* __restrict__ ksw,
                 const float* __restrict__ w1, const float* __restrict__ cb1,
                 const float* __restrict__ w2, const float* __restrict__ cb2,
                 float* __restrict__ out, int B, int S)
{
    const int tid = blockIdx.x * blockDim.x + threadIdx.x;
    const int e   = tid >> 2;          // batch element (4 lanes each)
    const int sub = threadIdx.x & 3;   // lane within quad: bit0 -> qubit2, bit1 -> qubit3
    if (e >= B) return;
    const bool b2 = (sub & 1) != 0, b3 = (sub >> 1) != 0;
    const float s2f = b2 ? -1.f : 1.f, s3f = b3 ? -1.f : 1.f;

    // ---- one-time: build the 16 Rot matrices (input-constant) into registers
    LayerC Lc[4];
    const float* PP[2] = { p1, p2 };
#pragma unroll
    for (int aI = 0; aI < 2; ++aI) {
        const float* pp = PP[aI];
#pragma unroll
        for (int l = 0; l < 2; ++l) {
            LayerC& L = Lc[aI*2 + l];
#pragma unroll
            for (int q = 0; q < 4; ++q) {
                float phi = pp[l*12 + q*3 + 0];
                float tht = pp[l*12 + q*3 + 1];
                float omg = pp[l*12 + q*3 + 2];
                float st, ct; sincosf(0.5f*tht, &st, &ct);
                float sA, cA, sB, cB;
                sincosf(0.5f*(phi + omg), &sA, &cA);
                sincosf(0.5f*(phi - omg), &sB, &cB);
                C2 u00 = {  cA*ct, -sA*ct };
                C2 u01 = { -cB*st, -sB*st };
                C2 u10 = {  cB*st, -sB*st };
                C2 u11 = {  cA*ct,  sA*ct };
                if      (q == 0) { L.m0[0]=u00; L.m0[1]=u01; L.m0[2]=u10; L.m0[3]=u11; }
                else if (q == 1) { L.m1[0]=u00; L.m1[1]=u01; L.m1[2]=u10; L.m1[3]=u11; }
                else if (q == 2) { L.a2 = b2 ? u11 : u00; L.b2 = b2 ? u10 : u01; }
                else             { L.a3 = b3 ? u11 : u00; L.b3 = b3 ? u10 : u01; }
            }
        }
    }

    // ---- per-lane KAN weights: lane j handles hidden dim j
    float bw[7], sw[7][4];
#pragma unroll
    for (int r = 0; r < 7; ++r) {
        bw[r] = kbw[r*4 + sub];
#pragma unroll
        for (int s = 0; s < 4; ++s) sw[r][s] = ksw[r*16 + sub*4 + s];
    }

    float ha[7];
#pragma unroll
    for (int k = 0; k < 7; ++k) ha[k] = initial_t[e*7 + k];

    const float4* inp4 = (const float4*)inputs;
    const long basei = (long)e * S;
    float4 xc = inp4[basei];

    float ev0 = 0.f, ev1 = 0.f, ev2 = 0.f, ev3 = 0.f;
    const float PI_ = 3.14159265358979323846f;

#pragma unroll 1
    for (int t = 0; t < S; ++t) {
        const int tn = (t + 1 < S) ? t + 1 : S - 1;
        float4 xn = inp4[basei + tn];   // prefetch next step's input

        C2 amp[4];
        // cell: |0000> -> fm(h_ang) -> ansatz(p1) -> fm(x_emb) -> ansatz(p2)
        fm_from_zero(amp, ha, s2f, s3f);
        apply_layer(amp, Lc[0], b3);
        apply_layer(amp, Lc[1], b3);

        float xe[7];
        xe[0] = xc.x; xe[1] = xc.y; xe[2] = xc.z; xe[3] = xc.w;
        xe[4] = (PI_ - xc.x) * (PI_ - xc.y);
        xe[5] = (PI_ - xc.y) * (PI_ - xc.z);
        xe[6] = (PI_ - xc.z) * (PI_ - xc.w);

        fm_h4_diag(amp, xe, s2f, s3f);
        apply_layer(amp, Lc[2], b3);
        apply_layer(amp, Lc[3], b3);

        // ---- measurement: <Z_q>, partial per lane then 2-round DPP butterfly
        float p0v = amp[0].r*amp[0].r + amp[0].i*amp[0].i;
        float p1v = amp[1].r*amp[1].r + amp[1].i*amp[1].i;
        float p2v = amp[2].r*amp[2].r + amp[2].i*amp[2].i;
        float p3v = amp[3].r*amp[3].r + amp[3].i*amp[3].i;
        float Ssum = p0v + p1v + p2v + p3v;
        float d0 = p0v - p1v + p2v - p3v;   // sign by local bit0 (q0)
        float d1 = p0v + p1v - p2v - p3v;   // sign by local bit1 (q1)
        float d2 = s2f * Ssum;              // sign by lane bit0 (q2)
        float d3 = s3f * Ssum;              // sign by lane bit1 (q3)
        d0 += lx1(d0); d0 += lx2(d0);
        d1 += lx1(d1); d1 += lx2(d1);
        d2 += lx1(d2); d2 += lx2(d2);
        d3 += lx1(d3); d3 += lx2(d3);
        ev0 = d0; ev1 = d1; ev2 = d2; ev3 = d3;

        // ---- KAN: lane j computes contribution of input dim j to all 7 outputs
        float xk = b3 ? (b2 ? ev3 : ev2) : (b2 ? ev1 : ev0);
        float sg = __fdividef(1.0f, 1.0f + __expf(-xk));
        float silu = xk * sg;
        // Cox-de-Boor exactly as reference (grid [-7,-5,...,7], h=2, order 3)
        float bb[7];
#pragma unroll
        for (int i2 = 0; i2 < 7; ++i2) {
            float g0 = 2.0f*(float)i2 - 7.0f;
            bb[i2] = (xk >= g0 && xk < g0 + 2.0f) ? 1.0f : 0.0f;
        }
        float c1v[6];
#pragma unroll
        for (int i2 = 0; i2 < 6; ++i2) {
            float gi  = 2.0f*(float)i2 - 7.0f;
            float gi2 = 2.0f*(float)(i2+2) - 7.0f;
            c1v[i2] = (xk - gi)*0.5f*bb[i2] + (gi2 - xk)*0.5f*bb[i2+1];
        }
        float c2v[5];
#pragma unroll
        for (int i2 = 0; i2 < 5; ++i2) {
            float gi  = 2.0f*(float)i2 - 7.0f;
            float gi3 = 2.0f*(float)(i2+3) - 7.0f;
            c2v[i2] = (xk - gi)*0.25f*c1v[i2] + (gi3 - xk)*0.25f*c1v[i2+1];
        }
        float c3v[4];
        const float inv6 = 1.0f/6.0f;
#pragma unroll
        for (int i2 = 0; i2 < 4; ++i2) {
            float gi  = 2.0f*(float)i2 - 7.0f;
            float gi4 = 2.0f*(float)(i2+4) - 7.0f;
            c3v[i2] = (xk - gi)*inv6*c2v[i2] + (gi4 - xk)*inv6*c2v[i2+1];
        }
#pragma unroll
        for (int r = 0; r < 7; ++r) {
            float o = silu*bw[r] + c3v[0]*sw[r][0] + c3v[1]*sw[r][1]
                    + c3v[2]*sw[r][2] + c3v[3]*sw[r][3];
            o += lx1(o); o += lx2(o);   // reduce over the 4 input dims (lanes)
            ha[r] = o;
        }

        xc = xn;
    }

    // ---- classifier head: relu(W1 h + b1) @ W2 + b2, lane 0 of each quad writes
    if (sub == 0) {
        float acc = cb2[0];
#pragma unroll
        for (int i = 0; i < 16; ++i) {
            float h = cb1[i] + w1[i*4+0]*ev0 + w1[i*4+1]*ev1
                    + w1[i*4+2]*ev2 + w1[i*4+3]*ev3;
            h = fmaxf(h, 0.0f);
            acc += w2[i]*h;
        }
        out[e] = acc;
    }
}

extern "C" void kernel_launch(void* const* d_in, const int* in_sizes, int n_in,
                              void* d_out, int out_size, void* d_ws, size_t ws_size,
                              hipStream_t stream) {
    const float* inputs    = (const float*)d_in[0];
    const float* initial_t = (const float*)d_in[1];
    const float* p1        = (const float*)d_in[2];
    const float* p2        = (const float*)d_in[3];
    const float* kbw       = (const float*)d_in[4];
    const float* ksw       = (const float*)d_in[5];
    const float* w1        = (const float*)d_in[6];
    const float* cb1       = (const float*)d_in[7];
    const float* w2        = (const float*)d_in[8];
    const float* cb2       = (const float*)d_in[9];

    const int B = in_sizes[1] / 7;            // 16384
    const int S = in_sizes[0] / (B * 4);      // 256

    const int threads = B * 4;                // 4 lanes per batch element
    const int block = 256;
    const int grid = (threads + block - 1) / block;   // 256 blocks -> 1/CU, 4 waves/CU

    qrnn_kernel<<<grid, block, 0, stream>>>(inputs, initial_t, p1, p2, kbw, ksw,
                                            w1, cb1, w2, cb2, (float*)d_out, B, S);
}

// Round 2
// 608.625 us; speedup vs baseline: 1.0636x; 1.0636x over previous
//
#include <hip/hip_runtime.h>
#include <math.h>

#define DEV static __device__ __forceinline__

struct C2 { float r, i; };

// DPP quad-perm helpers (all group-of-4 lane traffic; full VALU rate, no LDS)
template<int CTRL>
DEV float qperm(float x) {
    return __int_as_float(__builtin_amdgcn_mov_dpp(__float_as_int(x), CTRL, 0xF, 0xF, true));
}
DEV float lx1(float v) { return qperm<0xB1>(v); } // xor lane bit0: [1,0,3,2]
DEV float lx2(float v) { return qperm<0x4E>(v); } // xor lane bit1: [2,3,0,1]
// force a wave-uniform value into an SGPR
DEV float rfl(float x) { return __int_as_float(__builtin_amdgcn_readfirstlane(__float_as_int(x))); }

struct UniM { // wave-uniform (SGPR-resident) Rot matrices for qubits 0,1
    float a00r,a00i,a01r,a01i,a10r,a10i,a11r,a11i; // qubit0
    float b00r,b00i,b01r,b01i,b10r,b10i,b11r,b11i; // qubit1
};
struct LaneM { C2 a2,b2,a3,b3; }; // lane-selected coeffs for qubits 2,3 (VGPR)

// 2x2 complex unitary on a local amp pair; u-coeffs are scalars (1 SGPR/VALU op)
DEV void rot_pair(C2& x, C2& y,
                  float u00r,float u00i,float u01r,float u01i,
                  float u10r,float u10i,float u11r,float u11i) {
    float nxr = u00r*x.r - u00i*x.i + u01r*y.r - u01i*y.i;
    float nxi = u00r*x.i + u00i*x.r + u01r*y.i + u01i*y.r;
    float nyr = u10r*x.r - u10i*x.i + u11r*y.r - u11i*y.i;
    float nyi = u10r*x.i + u10i*x.r + u11r*y.i + u11i*y.r;
    x.r=nxr; x.i=nxi; y.r=nyr; y.i=nyi;
}

// Unitary on a lane-mapped qubit: new = al*own + be*partner (coeffs pre-selected)
template<int CTRL>
DEV void rot_lane(C2 a[4], C2 al, C2 be) {
#pragma unroll
    for (int m = 0; m < 4; ++m) {
        float pr = qperm<CTRL>(a[m].r);
        float pi = qperm<CTRL>(a[m].i);
        float nr = al.r*a[m].r - al.i*a[m].i + be.r*pr - be.i*pi;
        float ni = al.r*a[m].i + al.i*a[m].r + be.r*pi + be.i*pr;
        a[m].r = nr; a[m].i = ni;
    }
}

// One StronglyEntangling layer: Rot q0..q3 + CNOT ring (0,1)(1,2)(2,3)(3,0)
DEV void apply_layer(C2 a[4], const UniM& U, const LaneM& L, bool f3) {
    rot_pair(a[0],a[1], U.a00r,U.a00i,U.a01r,U.a01i,U.a10r,U.a10i,U.a11r,U.a11i);
    rot_pair(a[2],a[3], U.a00r,U.a00i,U.a01r,U.a01i,U.a10r,U.a10i,U.a11r,U.a11i);
    rot_pair(a[0],a[2], U.b00r,U.b00i,U.b01r,U.b01i,U.b10r,U.b10i,U.b11r,U.b11i);
    rot_pair(a[1],a[3], U.b00r,U.b00i,U.b01r,U.b01i,U.b10r,U.b10i,U.b11r,U.b11i);
    rot_lane<0xB1>(a, L.a2, L.b2);
    rot_lane<0x4E>(a, L.a3, L.b3);
    // CNOT(0,1): pure register relabel
    { C2 t = a[1]; a[1] = a[3]; a[3] = t; }
    // CNOT(1,2) and CNOT(2,3) merged into one quad_perm per amp:
    //   b1=0 amps: [0,3,2,1] (0x6C);  b1=1 amps: lx1 then [0,3,2,1] = [1,2,3,0] (0x39)
    a[0].r = qperm<0x6C>(a[0].r); a[0].i = qperm<0x6C>(a[0].i);
    a[1].r = qperm<0x6C>(a[1].r); a[1].i = qperm<0x6C>(a[1].i);
    a[2].r = qperm<0x39>(a[2].r); a[2].i = qperm<0x39>(a[2].i);
    a[3].r = qperm<0x39>(a[3].r); a[3].i = qperm<0x39>(a[3].i);
    // CNOT(3,0): lanes with b3=1 swap local bit0
#pragma unroll
    for (int m = 0; m < 4; m += 2) {
        float t0r = f3 ? a[m+1].r : a[m].r;
        float t0i = f3 ? a[m+1].i : a[m].i;
        float t1r = f3 ? a[m].r   : a[m+1].r;
        float t1i = f3 ? a[m].i   : a[m+1].i;
        a[m].r = t0r; a[m].i = t0i; a[m+1].r = t1r; a[m+1].i = t1i;
    }
}

// sig[m] = -theta_m/2 given NEGATED-HALF angles h[k] = -0.5*angle_k (linear fold)
DEV void diag_sig(const float* h, float s2f, float s3f, float s23, float sig[4]) {
    float Lx = s2f*h[2] + s3f*h[3] + s23*h[6];
    float u  = s2f*h[5];
    float P = Lx + u, Q = Lx - u;
    float ep = h[0] + h[1], em = h[0] - h[1];
    sig[0] = ep + (P + h[4]);
    sig[1] = (P - h[4]) - em;
    sig[2] = em + (Q - h[4]);
    sig[3] = (Q + h[4]) - ep;
}

// feature_map on |0000>, 1/4 scale dropped (folded into final 1/256): amp = e^{i sig}
DEV void fm_from_zero(C2 a[4], const float* h, float s2f, float s3f, float s23) {
    float sig[4];
    diag_sig(h, s2f, s3f, s23, sig);
#pragma unroll
    for (int m = 0; m < 4; ++m) {
        float s, c; __sincosf(sig[m], &s, &c);
        a[m].r = c; a[m].i = s;
    }
}

// feature_map on live state: unscaled H^{x4} then diag phase (scale folded out)
DEV void fm_h4_diag(C2 a[4], const float* h, float s2f, float s3f, float s23) {
    { // H q0: pairs (0,1),(2,3)
        C2 n0={a[0].r+a[1].r,a[0].i+a[1].i}, n1={a[0].r-a[1].r,a[0].i-a[1].i};
        C2 n2={a[2].r+a[3].r,a[2].i+a[3].i}, n3={a[2].r-a[3].r,a[2].i-a[3].i};
        a[0]=n0; a[1]=n1; a[2]=n2; a[3]=n3;
    }
    { // H q1: pairs (0,2),(1,3)
        C2 n0={a[0].r+a[2].r,a[0].i+a[2].i}, n2={a[0].r-a[2].r,a[0].i-a[2].i};
        C2 n1={a[1].r+a[3].r,a[1].i+a[3].i}, n3={a[1].r-a[3].r,a[1].i-a[3].i};
        a[0]=n0; a[1]=n1; a[2]=n2; a[3]=n3;
    }
#pragma unroll
    for (int m = 0; m < 4; ++m) { // H q2 (lane bit0): new = partner + s*own
        float pr = lx1(a[m].r), pi = lx1(a[m].i);
        a[m].r = fmaf(s2f, a[m].r, pr);
        a[m].i = fmaf(s2f, a[m].i, pi);
    }
#pragma unroll
    for (int m = 0; m < 4; ++m) { // H q3 (lane bit1)
        float pr = lx2(a[m].r), pi = lx2(a[m].i);
        a[m].r = fmaf(s3f, a[m].r, pr);
        a[m].i = fmaf(s3f, a[m].i, pi);
    }
    float sig[4];
    diag_sig(h, s2f, s3f, s23, sig);
#pragma unroll
    for (int m = 0; m < 4; ++m) { // amp *= (c + i s), sig = -theta/2
        float s, c; __sincosf(sig[m], &s, &c);
        float nr = a[m].r*c - a[m].i*s;
        float ni = a[m].i*c + a[m].r*s;
        a[m].r = nr; a[m].i = ni;
    }
}

__global__ __launch_bounds__(256, 1)
void qrnn_kernel(const float* __restrict__ inputs, const float* __restrict__ initial_t,
                 const float* __restrict__ p1, const float* __restrict__ p2,
                 const float* __restrict__ kbw, const float* __restrict__ ksw,
                 const float* __restrict__ w1, const float* __restrict__ cb1,
                 const float* __restrict__ w2, const float* __restrict__ cb2,
                 float* __restrict__ out, int B, int S)
{
    const int tid = blockIdx.x * blockDim.x + threadIdx.x;
    const int e   = tid >> 2;
    const int sub = threadIdx.x & 3;   // lane bit0 -> qubit2, bit1 -> qubit3
    if (e >= B) return;
    const bool b2 = (sub & 1) != 0, b3 = (sub & 2) != 0;
    const float s2f = b2 ? -1.f : 1.f, s3f = b3 ? -1.f : 1.f;
    const float s23 = s2f * s3f;
    const float k0c = (sub == 3) ? -1.f : 1.f;  // chain-C prep sign
    const float sg1 = -s23;                     // chain-C round-1 sign

    // ---- one-time: 16 Rot matrices. q0/q1 coeffs are wave-uniform -> SGPRs.
    UniM U[4]; LaneM L[4];
    const float* PP[2] = { p1, p2 };
#pragma unroll
    for (int aI = 0; aI < 2; ++aI) {
        const float* pp = PP[aI];
#pragma unroll
        for (int l = 0; l < 2; ++l) {
            const int idx = aI*2 + l;
#pragma unroll
            for (int q = 0; q < 4; ++q) {
                float phi = pp[l*12 + q*3 + 0];
                float tht = pp[l*12 + q*3 + 1];
                float omg = pp[l*12 + q*3 + 2];
                float st, ct; sincosf(0.5f*tht, &st, &ct);
                float sA, cA, sB, cB;
                sincosf(0.5f*(phi + omg), &sA, &cA);
                sincosf(0.5f*(phi - omg), &sB, &cB);
                C2 u00 = {  cA*ct, -sA*ct };
                C2 u01 = { -cB*st, -sB*st };
                C2 u10 = {  cB*st, -sB*st };
                C2 u11 = {  cA*ct,  sA*ct };
                if (q == 0) {
                    U[idx].a00r=rfl(u00.r); U[idx].a00i=rfl(u00.i);
                    U[idx].a01r=rfl(u01.r); U[idx].a01i=rfl(u01.i);
                    U[idx].a10r=rfl(u10.r); U[idx].a10i=rfl(u10.i);
                    U[idx].a11r=rfl(u11.r); U[idx].a11i=rfl(u11.i);
                } else if (q == 1) {
                    U[idx].b00r=rfl(u00.r); U[idx].b00i=rfl(u00.i);
                    U[idx].b01r=rfl(u01.r); U[idx].b01i=rfl(u01.i);
                    U[idx].b10r=rfl(u10.r); U[idx].b10i=rfl(u10.i);
                    U[idx].b11r=rfl(u11.r); U[idx].b11i=rfl(u11.i);
                } else if (q == 2) {
                    L[idx].a2 = b2 ? u11 : u00; L[idx].b2 = b2 ? u10 : u01;
                } else {
                    L[idx].a3 = b3 ? u11 : u00; L[idx].b3 = b3 ? u10 : u01;
                }
            }
        }
    }

    // ---- KAN: lane j = input dim j. Spline basis over [-1,1] collapses to
    // closed-form cubics: 48*c3 = {(1-x)^3, 23-15x-3x^2+3x^3, 23+15x-3x^2-3x^3,
    // (1+x)^3}. Fold spline weights + the -0.5 half-angle convention into
    // per-output polynomial coeffs (exact algebra, C^2 at knots).
    float Q0[7], Q1[7], Q2[7], Q3[7], BW[7];
#pragma unroll
    for (int r = 0; r < 7; ++r) {
        float sw0 = ksw[r*16 + sub*4 + 0], sw1 = ksw[r*16 + sub*4 + 1];
        float sw2 = ksw[r*16 + sub*4 + 2], sw3 = ksw[r*16 + sub*4 + 3];
        const float f = -0.5f / 48.0f;
        Q0[r] = f * (sw0 + 23.f*sw1 + 23.f*sw2 + sw3);
        Q1[r] = f * (-3.f*sw0 - 15.f*sw1 + 15.f*sw2 + 3.f*sw3);
        Q2[r] = f * (3.f*sw0 - 3.f*sw1 - 3.f*sw2 + 3.f*sw3);
        Q3[r] = f * (-sw0 + 3.f*sw1 - 3.f*sw2 + sw3);
        BW[r] = -0.5f * kbw[r*4 + sub];
    }

    // hidden angles stored NEGATED-HALVED: h = -0.5*angle
    float ha[7];
#pragma unroll
    for (int k = 0; k < 7; ++k) ha[k] = -0.5f * initial_t[e*7 + k];

    const float4* inp4 = (const float4*)inputs;
    const long basei = (long)e * S;
    float4 xc = inp4[basei];

    const float PI_  = 3.14159265358979323846f;
    const float NHPI = -1.57079632679489661923f;
    float xk = 0.f;

#pragma unroll 1
    for (int t = 0; t < S; ++t) {
        const int tn = (t + 1 < S) ? t + 1 : S - 1;
        float4 xn = inp4[basei + tn];   // prefetch next input

        C2 amp[4];
        fm_from_zero(amp, ha, s2f, s3f, s23);
        apply_layer(amp, U[0], L[0], b3);
        apply_layer(amp, U[1], L[1], b3);

        // embed x, negated-halved: he = -0.5*xe
        float he[7];
        float hx0 = -0.5f*xc.x, hx1 = -0.5f*xc.y, hx2 = -0.5f*xc.z, hx3 = -0.5f*xc.w;
        he[0]=hx0; he[1]=hx1; he[2]=hx2; he[3]=hx3;
        float v0 = fmaf(2.f, hx0, PI_);   // pi - x0
        float v1 = fmaf(2.f, hx1, PI_);
        float v2 = fmaf(2.f, hx2, PI_);
        float w1_ = NHPI - hx1;           // -(pi - x1)/2
        float w2_ = NHPI - hx2;
        float w3_ = NHPI - hx3;
        he[4] = v0*w1_; he[5] = v1*w2_; he[6] = v2*w3_;

        fm_h4_diag(amp, he, s2f, s3f, s23);
        apply_layer(amp, U[2], L[2], b3);
        apply_layer(amp, U[3], L[3], b3);

        // ---- measurement (probs carry x256; fold 1/256 into xk)
        float p0 = amp[0].r*amp[0].r + amp[0].i*amp[0].i;
        float pq1 = amp[1].r*amp[1].r + amp[1].i*amp[1].i;
        float pq2 = amp[2].r*amp[2].r + amp[2].i*amp[2].i;
        float pq3 = amp[3].r*amp[3].r + amp[3].i*amp[3].i;
        float s01 = p0 + pq1, s23p = pq2 + pq3;
        float d01 = p0 - pq1, d23 = pq2 - pq3;
        float Sm = s01 + s23p;
        float t0 = d01 + d23;              // qubit0 sign combo
        float t1 = s01 - s23p;             // qubit1 sign combo
        float ea = t0 + lx1(t0); ea += lx2(ea);     // lane0 <- 256*ev0
        float eb = t1 + lx1(t1); eb += lx2(eb);     // lane1 <- 256*ev1
        float u = k0c * Sm;                          // sign-twisted butterfly:
        u = fmaf(sg1, lx1(u), u);                    // lane2 <- 256*ev2
        u += lx2(u);                                 // lane3 <- 256*ev3
        xk = b3 ? u : (b2 ? eb : ea);
        xk *= (1.0f/256.0f);               // lane j now holds true ev_j in [-1,1]

        // ---- KAN (folded -0.5): ha[r] = -0.5 * (silu path + spline path)
        float eneg = __expf(-xk);
        float silu = __fdividef(xk, 1.0f + eneg);
#pragma unroll
        for (int r = 0; r < 7; ++r) {
            float o = fmaf(Q3[r], xk, Q2[r]);
            o = fmaf(o, xk, Q1[r]);
            o = fmaf(o, xk, Q0[r]);
            o = fmaf(BW[r], silu, o);
            o += lx1(o); o += lx2(o);      // sum over 4 input dims (lanes)
            ha[r] = o;
        }

        xc = xn;
    }

    // ---- classifier head: lane j holds ev_j; gather to lane 0
    float ev1 = qperm<0x55>(xk);
    float ev2 = qperm<0xAA>(xk);
    float ev3 = qperm<0xFF>(xk);
    if (sub == 0) {
        float acc = cb2[0];
#pragma unroll
        for (int i = 0; i < 16; ++i) {
            float h = cb1[i] + w1[i*4+0]*xk + w1[i*4+1]*ev1
                    + w1[i*4+2]*ev2 + w1[i*4+3]*ev3;
            h = fmaxf(h, 0.0f);
            acc += w2[i]*h;
        }
        out[e] = acc;
    }
}

extern "C" void kernel_launch(void* const* d_in, const int* in_sizes, int n_in,
                              void* d_out, int out_size, void* d_ws, size_t ws_size,
                              hipStream_t stream) {
    const float* inputs    = (const float*)d_in[0];
    const float* initial_t = (const float*)d_in[1];
    const float* p1        = (const float*)d_in[2];
    const float* p2        = (const float*)d_in[3];
    const float* kbw       = (const float*)d_in[4];
    const float* ksw       = (const float*)d_in[5];
    const float* w1        = (const float*)d_in[6];
    const float* cb1       = (const float*)d_in[7];
    const float* w2        = (const float*)d_in[8];
    const float* cb2       = (const float*)d_in[9];

    const int B = in_sizes[1] / 7;            // 16384
    const int S = in_sizes[0] / (B * 4);      // 256

    const int threads = B * 4;                // 4 lanes per batch element
    const int block = 256;
    const int grid = (threads + block - 1) / block;

    qrnn_kernel<<<grid, block, 0, stream>>>(inputs, initial_t, p1, p2, kbw, ksw,
                                            w1, cb1, w2, cb2, (float*)d_out, B, S);
}

// Round 3
// 575.866 us; speedup vs baseline: 1.1241x; 1.0569x over previous
//
#include <hip/hip_runtime.h>
#include <math.h>

#define DEV static __device__ __forceinline__

struct C2 { float r, i; };

// DPP helpers — ALL cross-lane traffic is full-rate VALU DPP (no LDS pipe).
template<int CTRL>
DEV float qperm(float x) {
    return __int_as_float(__builtin_amdgcn_mov_dpp(__float_as_int(x), CTRL, 0xF, 0xF, true));
}
DEV float lx1(float v)  { return qperm<0xB1>(v); }  // quad: xor lane bit0 (qubit2)
DEV float lx2(float v)  { return qperm<0x4E>(v); }  // quad: xor lane bit1 (qubit3)
DEV float ror8(float v) { return qperm<0x128>(v); } // row_ror:8 = xor lane bit3 (qubit1)
DEV float rfl(float x)  { return __int_as_float(__builtin_amdgcn_readfirstlane(__float_as_int(x))); }

// Rot on the register-local qubit0: x'=u00 x+u01 y; y'=-conj(u01) x+conj(u00) y.
// S=u00, T=u01 wave-uniform (SGPR); each FMA reads exactly 1 SGPR.
DEV void rot_q0(C2& x, C2& y, float Sr, float Si, float Tr, float Ti) {
    float nxr = Sr*x.r; nxr = fmaf(-Si, x.i, nxr); nxr = fmaf( Tr, y.r, nxr); nxr = fmaf(-Ti, y.i, nxr);
    float nxi = Sr*x.i; nxi = fmaf( Si, x.r, nxi); nxi = fmaf( Tr, y.i, nxi); nxi = fmaf( Ti, y.r, nxi);
    float nyr = Sr*y.r; nyr = fmaf( Si, y.i, nyr); nyr = fmaf(-Tr, x.r, nyr); nyr = fmaf(-Ti, x.i, nyr);
    float nyi = Sr*y.i; nyi = fmaf(-Si, y.r, nyi); nyi = fmaf(-Tr, x.i, nyi); nyi = fmaf( Ti, x.r, nyi);
    x.r=nxr; x.i=nxi; y.r=nyr; y.i=nyi;
}

// Rot on a lane-distributed qubit; u11=conj(u00), u10=-conj(u01) => coeffs are
// {Ur(SGPR), vAI=z*u00.i(VGPR), vBR=z*u01.r(VGPR), Wi(SGPR)}. p = partner amp.
DEV void rot_d(C2& a, float pr, float pi, float Ur, float Wi, float vAI, float vBR) {
    float nr = Ur*a.r;
    nr = fmaf(-vAI, a.i, nr);
    nr = fmaf( vBR, pr,  nr);
    nr = fmaf(-Wi,  pi,  nr);
    float ni = Ur*a.i;
    ni = fmaf( vAI, a.r, ni);
    ni = fmaf( vBR, pi,  ni);
    ni = fmaf( Wi,  pr,  ni);
    a.r = nr; a.i = ni;
}

__global__ __launch_bounds__(256, 2)
void qrnn_kernel(const float* __restrict__ inputs, const float* __restrict__ initial_t,
                 const float* __restrict__ p1, const float* __restrict__ p2,
                 const float* __restrict__ kbw, const float* __restrict__ ksw,
                 const float* __restrict__ w1, const float* __restrict__ cb1,
                 const float* __restrict__ w2, const float* __restrict__ cb2,
                 float* __restrict__ out, int B, int S)
{
    // 8 lanes/element, two elements interleaved per 16-lane DPP row:
    // lane bit0->qubit2, bit1->qubit3, bit3->qubit1; bit2 selects the element.
    const int tid    = blockIdx.x * blockDim.x + threadIdx.x;
    const int lane16 = threadIdx.x & 15;
    const int e      = (tid >> 4) * 2 + ((lane16 >> 2) & 1);
    const int sub    = lane16 & 3;
    const bool b1    = ((lane16 >> 3) & 1) != 0;
    if (e >= B) return;
    const bool b2 = (sub & 1) != 0, b3 = (sub & 2) != 0;
    const float z2f = b2 ? -1.f : 1.f;
    const float z3f = b3 ? -1.f : 1.f;
    const float z1f = b1 ? -1.f : 1.f;
    const float z12 = z1f * z2f, z23 = z2f * z3f;
    const float k0c = (sub == 3) ? -1.f : 1.f;
    const float sg1 = -z23;

    // ---- one-time: 16 Rot matrices (input-constant)
    float Ls[4][4];              // qubit0 {Sr,Si,Tr,Ti} (SGPR via rfl)
    float LUr[4][3], LWi[4][3];  // distributed-qubit uniform parts (SGPR)
    float LvA[4][3], LvB[4][3];  // distributed-qubit lane-signed parts (VGPR)
    const float* PP[2] = { p1, p2 };
#pragma unroll
    for (int aI = 0; aI < 2; ++aI) {
        const float* pp = PP[aI];
#pragma unroll
        for (int l = 0; l < 2; ++l) {
            const int idx = aI*2 + l;
#pragma unroll
            for (int q = 0; q < 4; ++q) {
                float phi = pp[l*12 + q*3 + 0];
                float tht = pp[l*12 + q*3 + 1];
                float omg = pp[l*12 + q*3 + 2];
                float st, ct; sincosf(0.5f*tht, &st, &ct);
                float sA, cA, sB, cB;
                sincosf(0.5f*(phi + omg), &sA, &cA);
                sincosf(0.5f*(phi - omg), &sB, &cB);
                C2 u00 = {  cA*ct, -sA*ct };
                C2 u01 = { -cB*st, -sB*st };
                if (q == 0) {
                    Ls[idx][0]=rfl(u00.r); Ls[idx][1]=rfl(u00.i);
                    Ls[idx][2]=rfl(u01.r); Ls[idx][3]=rfl(u01.i);
                } else {
                    float zq = (q == 1) ? z1f : (q == 2) ? z2f : z3f;
                    LUr[idx][q-1] = rfl(u00.r);
                    LWi[idx][q-1] = rfl(u01.i);
                    LvA[idx][q-1] = zq * u00.i;
                    LvB[idx][q-1] = zq * u01.r;
                }
            }
        }
    }

    // ---- KAN poly coeffs (lane 'sub' = input dim), -0.5 convention folded in
    float Q0[7], Q1[7], Q2[7], Q3[7], BW[7];
#pragma unroll
    for (int r = 0; r < 7; ++r) {
        float sw0 = ksw[r*16 + sub*4 + 0], sw1 = ksw[r*16 + sub*4 + 1];
        float sw2 = ksw[r*16 + sub*4 + 2], sw3 = ksw[r*16 + sub*4 + 3];
        const float f = -0.5f / 48.0f;
        Q0[r] = f * (sw0 + 23.f*sw1 + 23.f*sw2 + sw3);
        Q1[r] = f * (-3.f*sw0 - 15.f*sw1 + 15.f*sw2 + 3.f*sw3);
        Q2[r] = f * (3.f*sw0 - 3.f*sw1 - 3.f*sw2 + 3.f*sw3);
        Q3[r] = f * (-sw0 + 3.f*sw1 - 3.f*sw2 + sw3);
        BW[r] = -0.5f * kbw[r*4 + sub];
    }

    float ha[7];  // NEGATED-HALVED hidden angles
#pragma unroll
    for (int k = 0; k < 7; ++k) ha[k] = -0.5f * initial_t[e*7 + k];

    const float4* inp4 = (const float4*)inputs;
    const long basei = (long)e * S;
    float4 xc = inp4[basei];

    const float PI_  = 3.14159265358979323846f;
    const float NHPI = -1.57079632679489661923f;
    float xk = 0.f;

#pragma unroll 1
    for (int t = 0; t < S; ++t) {
        const int tn = (t + 1 < S) ? t + 1 : S - 1;
        float4 xn = inp4[basei + tn];

        C2 a0, a1;

        // ---- fm(hidden) on |0000>: amp = e^{i sig}
        {
            float base = ha[1]*z1f;
            base = fmaf(ha[2], z2f, base);
            base = fmaf(ha[3], z3f, base);
            base = fmaf(ha[5], z12, base);
            base = fmaf(ha[6], z23, base);
            float w = fmaf(ha[4], z1f, ha[0]);
            float s0, c0, s1, c1;
            __sincosf(base + w, &s0, &c0);
            __sincosf(base - w, &s1, &c1);
            a0.r = c0; a0.i = s0;
            a1.r = c1; a1.i = s1;
        }

        // ---- ansatz(p1) then fm(x) then ansatz(p2): two 2-layer loops
#pragma unroll
        for (int half = 0; half < 2; ++half) {
#pragma unroll
            for (int li = 0; li < 2; ++li) {
                const int l = half*2 + li;
                rot_q0(a0, a1, Ls[l][0], Ls[l][1], Ls[l][2], Ls[l][3]);
                { float pr = ror8(a0.r), pi = ror8(a0.i);
                  float qr = ror8(a1.r), qi = ror8(a1.i);
                  rot_d(a0, pr, pi, LUr[l][0], LWi[l][0], LvA[l][0], LvB[l][0]);
                  rot_d(a1, qr, qi, LUr[l][0], LWi[l][0], LvA[l][0], LvB[l][0]); }
                { float pr = lx1(a0.r), pi = lx1(a0.i);
                  float qr = lx1(a1.r), qi = lx1(a1.i);
                  rot_d(a0, pr, pi, LUr[l][1], LWi[l][1], LvA[l][1], LvB[l][1]);
                  rot_d(a1, qr, qi, LUr[l][1], LWi[l][1], LvA[l][1], LvB[l][1]); }
                { float pr = lx2(a0.r), pi = lx2(a0.i);
                  float qr = lx2(a1.r), qi = lx2(a1.i);
                  rot_d(a0, pr, pi, LUr[l][2], LWi[l][2], LvA[l][2], LvB[l][2]);
                  rot_d(a1, qr, qi, LUr[l][2], LWi[l][2], LvA[l][2], LvB[l][2]); }
                // CNOT(0,1)
                a1.r = ror8(a1.r); a1.i = ror8(a1.i);
                // CNOT(1,2) o CNOT(2,3): b1=0 -> 0x6C; b1=1 -> 0x39
                { float vA, vB;
                  vA = qperm<0x6C>(a0.r); vB = qperm<0x39>(a0.r); a0.r = b1 ? vB : vA;
                  vA = qperm<0x6C>(a0.i); vB = qperm<0x39>(a0.i); a0.i = b1 ? vB : vA;
                  vA = qperm<0x6C>(a1.r); vB = qperm<0x39>(a1.r); a1.r = b1 ? vB : vA;
                  vA = qperm<0x6C>(a1.i); vB = qperm<0x39>(a1.i); a1.i = b1 ? vB : vA; }
                // CNOT(3,0): lanes with q3=1 swap local amps
                { float t0r = b3 ? a1.r : a0.r, t0i = b3 ? a1.i : a0.i;
                  float t1r = b3 ? a0.r : a1.r, t1i = b3 ? a0.i : a1.i;
                  a0.r = t0r; a0.i = t0i; a1.r = t1r; a1.i = t1i; }
            }
            if (half == 0) {
                // ---- fm(x_embed): H^{x4} (unscaled) + diag phase
                float he[7];
                float hx0 = -0.5f*xc.x, hx1 = -0.5f*xc.y, hx2 = -0.5f*xc.z, hx3 = -0.5f*xc.w;
                he[0]=hx0; he[1]=hx1; he[2]=hx2; he[3]=hx3;
                float v0 = fmaf(2.f, hx0, PI_);
                float v1 = fmaf(2.f, hx1, PI_);
                float v2 = fmaf(2.f, hx2, PI_);
                float w1_ = NHPI - hx1;
                float w2_ = NHPI - hx2;
                float w3_ = NHPI - hx3;
                he[4] = v0*w1_; he[5] = v1*w2_; he[6] = v2*w3_;

                C2 n0 = { a0.r + a1.r, a0.i + a1.i };
                C2 n1 = { a0.r - a1.r, a0.i - a1.i };
                a0 = n0; a1 = n1;
                { float pr = ror8(a0.r), pi = ror8(a0.i);
                  a0.r = fmaf(z1f, a0.r, pr); a0.i = fmaf(z1f, a0.i, pi);
                  float qr = ror8(a1.r), qi = ror8(a1.i);
                  a1.r = fmaf(z1f, a1.r, qr); a1.i = fmaf(z1f, a1.i, qi); }
                { float pr = lx1(a0.r), pi = lx1(a0.i);
                  a0.r = fmaf(z2f, a0.r, pr); a0.i = fmaf(z2f, a0.i, pi);
                  float qr = lx1(a1.r), qi = lx1(a1.i);
                  a1.r = fmaf(z2f, a1.r, qr); a1.i = fmaf(z2f, a1.i, qi); }
                { float pr = lx2(a0.r), pi = lx2(a0.i);
                  a0.r = fmaf(z3f, a0.r, pr); a0.i = fmaf(z3f, a0.i, pi);
                  float qr = lx2(a1.r), qi = lx2(a1.i);
                  a1.r = fmaf(z3f, a1.r, qr); a1.i = fmaf(z3f, a1.i, qi); }
                float base = he[1]*z1f;
                base = fmaf(he[2], z2f, base);
                base = fmaf(he[3], z3f, base);
                base = fmaf(he[5], z12, base);
                base = fmaf(he[6], z23, base);
                float w = fmaf(he[4], z1f, he[0]);
                float s0, c0, s1, c1;
                __sincosf(base + w, &s0, &c0);
                __sincosf(base - w, &s1, &c1);
                float nr0 = a0.r*c0 - a0.i*s0, ni0 = a0.i*c0 + a0.r*s0;
                float nr1 = a1.r*c1 - a1.i*s1, ni1 = a1.i*c1 + a1.r*s1;
                a0.r = nr0; a0.i = ni0; a1.r = nr1; a1.i = ni1;
            }
        }

        // ---- measurement (probs carry x256; scale folded into xk)
        float p0 = fmaf(a0.i, a0.i, a0.r*a0.r);
        float pq = fmaf(a1.i, a1.i, a1.r*a1.r);
        float s  = p0 + pq;
        float d  = p0 - pq;
        float ea = d + lx1(d);   ea += lx2(ea); ea += ror8(ea);   // 256*ev0 (all lanes)
        float t1 = z1f * s;
        float eb = t1 + lx1(t1); eb += lx2(eb); eb += ror8(eb);   // 256*ev1 (all lanes)
        float u = k0c * s;                                        // twisted chain:
        u = fmaf(sg1, lx1(u), u);                                 //  sub2 -> 256*ev2
        u += lx2(u);                                              //  sub3 -> 256*ev3
        u += ror8(u);
        xk = b3 ? u : (b2 ? eb : ea);
        xk *= (1.0f/256.0f);

        // ---- KAN: lane sub = dim; quad-reduce sums the 4 dims
        float eneg = __expf(-xk);
        float silu = __fdividef(xk, 1.0f + eneg);
#pragma unroll
        for (int r = 0; r < 7; ++r) {
            float o = fmaf(Q3[r], xk, Q2[r]);
            o = fmaf(o, xk, Q1[r]);
            o = fmaf(o, xk, Q0[r]);
            o = fmaf(BW[r], silu, o);
            o += lx1(o); o += lx2(o);
            ha[r] = o;
        }

        xc = xn;
    }

    // ---- classifier head: quad lanes hold ev0..ev3
    float ev1 = qperm<0x55>(xk);
    float ev2 = qperm<0xAA>(xk);
    float ev3 = qperm<0xFF>(xk);
    if (sub == 0 && !b1) {
        float acc = cb2[0];
#pragma unroll
        for (int i = 0; i < 16; ++i) {
            float h = cb1[i] + w1[i*4+0]*xk + w1[i*4+1]*ev1
                    + w1[i*4+2]*ev2 + w1[i*4+3]*ev3;
            h = fmaxf(h, 0.0f);
            acc += w2[i]*h;
        }
        out[e] = acc;
    }
}

extern "C" void kernel_launch(void* const* d_in, const int* in_sizes, int n_in,
                              void* d_out, int out_size, void* d_ws, size_t ws_size,
                              hipStream_t stream) {
    const float* inputs    = (const float*)d_in[0];
    const float* initial_t = (const float*)d_in[1];
    const float* p1        = (const float*)d_in[2];
    const float* p2        = (const float*)d_in[3];
    const float* kbw       = (const float*)d_in[4];
    const float* ksw       = (const float*)d_in[5];
    const float* w1        = (const float*)d_in[6];
    const float* cb1       = (const float*)d_in[7];
    const float* w2        = (const float*)d_in[8];
    const float* cb2       = (const float*)d_in[9];

    const int B = in_sizes[1] / 7;            // 16384
    const int S = in_sizes[0] / (B * 4);      // 256

    const int threads = B * 8;                // 8 lanes per batch element
    const int block = 256;
    const int grid = (threads + block - 1) / block;   // 512 blocks -> 8 waves/CU

    qrnn_kernel<<<grid, block, 0, stream>>>(inputs, initial_t, p1, p2, kbw, ksw,
                                            w1, cb1, w2, cb2, (float*)d_out, B, S);
}

// Round 4
// 559.487 us; speedup vs baseline: 1.1570x; 1.0293x over previous
//
#include <hip/hip_runtime.h>
#include <math.h>

#define DEV static __device__ __forceinline__

struct C2 { float r, i; };

// DPP helpers — ALL cross-lane traffic is full-rate VALU DPP (no LDS pipe).
template<int CTRL>
DEV float qperm(float x) {
    return __int_as_float(__builtin_amdgcn_mov_dpp(__float_as_int(x), CTRL, 0xF, 0xF, true));
}
DEV float lx1(float v)  { return qperm<0xB1>(v); }  // quad: xor lane bit0 (qubit2)
DEV float lx2(float v)  { return qperm<0x4E>(v); }  // quad: xor lane bit1 (qubit3)
DEV float ror8(float v) { return qperm<0x128>(v); } // row_ror:8 = xor lane bit3 (qubit1)
DEV float rfl(float x)  { return __int_as_float(__builtin_amdgcn_readfirstlane(__float_as_int(x))); }

// Cheap sincos in REVOLUTIONS: v_fract + v_sin + v_cos (3 inst, no OCML).
DEV void fsincos(float rev, float* s, float* c) {
    float f = __builtin_amdgcn_fractf(rev);
    *s = __builtin_amdgcn_sinf(f);
    *c = __builtin_amdgcn_cosf(f);
}

// Rot on the register-local qubit0: x'=u00 x+u01 y; y'=-conj(u01) x+conj(u00) y.
// S=u00, T=u01 wave-uniform (SGPR); each FMA reads exactly 1 SGPR.
DEV void rot_q0(C2& x, C2& y, float Sr, float Si, float Tr, float Ti) {
    float nxr = Sr*x.r; nxr = fmaf(-Si, x.i, nxr); nxr = fmaf( Tr, y.r, nxr); nxr = fmaf(-Ti, y.i, nxr);
    float nxi = Sr*x.i; nxi = fmaf( Si, x.r, nxi); nxi = fmaf( Tr, y.i, nxi); nxi = fmaf( Ti, y.r, nxi);
    float nyr = Sr*y.r; nyr = fmaf( Si, y.i, nyr); nyr = fmaf(-Tr, x.r, nyr); nyr = fmaf(-Ti, x.i, nyr);
    float nyi = Sr*y.i; nyi = fmaf(-Si, y.r, nyi); nyi = fmaf(-Tr, x.i, nyi); nyi = fmaf( Ti, x.r, nyi);
    x.r=nxr; x.i=nxi; y.r=nyr; y.i=nyi;
}

// Rot on a lane-distributed qubit; u11=conj(u00), u10=-conj(u01) => coeffs are
// {Ur(SGPR), vAI=z*u00.i(VGPR), vBR=z*u01.r(VGPR), Wi(SGPR)}. p = partner amp.
DEV void rot_d(C2& a, float pr, float pi, float Ur, float Wi, float vAI, float vBR) {
    float nr = Ur*a.r;
    nr = fmaf(-vAI, a.i, nr);
    nr = fmaf( vBR, pr,  nr);
    nr = fmaf(-Wi,  pi,  nr);
    float ni = Ur*a.i;
    ni = fmaf( vAI, a.r, ni);
    ni = fmaf( vBR, pi,  ni);
    ni = fmaf( Wi,  pr,  ni);
    a.r = nr; a.i = ni;
}

__global__ __launch_bounds__(256, 2)
void qrnn_kernel(const float* __restrict__ inputs, const float* __restrict__ initial_t,
                 const float* __restrict__ p1, const float* __restrict__ p2,
                 const float* __restrict__ kbw, const float* __restrict__ ksw,
                 const float* __restrict__ w1, const float* __restrict__ cb1,
                 const float* __restrict__ w2, const float* __restrict__ cb2,
                 float* __restrict__ out, int B, int S)
{
    // 8 lanes/element, two elements interleaved per 16-lane DPP row:
    // lane bit0->qubit2, bit1->qubit3, bit3->qubit1; bit2 selects the element.
    const int tid    = blockIdx.x * blockDim.x + threadIdx.x;
    const int lane16 = threadIdx.x & 15;
    const int e      = (tid >> 4) * 2 + ((lane16 >> 2) & 1);
    const int sub    = lane16 & 3;
    const bool b1    = ((lane16 >> 3) & 1) != 0;
    if (e >= B) return;
    const bool b2 = (sub & 1) != 0, b3 = (sub & 2) != 0;
    const float z2f = b2 ? -1.f : 1.f;
    const float z3f = b3 ? -1.f : 1.f;
    const float z1f = b1 ? -1.f : 1.f;
    const float z12 = z1f * z2f, z23 = z2f * z3f;
    const float k0c = (sub == 3) ? -1.f : 1.f;
    const float sg1 = -z23;

    // All angles carried in REVOLUTIONS with the -0.5 half-angle convention
    // folded in: stored = -angle_rad/(4*pi).
    const float REVC = -0.07957747154594767f;   // -1/(4*pi)

    // ---- one-time: 16 Rot matrices (input-constant; cold path keeps libm)
    float Ls[4][4];              // qubit0 {Sr,Si,Tr,Ti} (SGPR via rfl)
    float LUr[4][3], LWi[4][3];  // distributed-qubit uniform parts (SGPR)
    float LvA[4][3], LvB[4][3];  // distributed-qubit lane-signed parts (VGPR)
    const float* PP[2] = { p1, p2 };
#pragma unroll
    for (int aI = 0; aI < 2; ++aI) {
        const float* pp = PP[aI];
#pragma unroll
        for (int l = 0; l < 2; ++l) {
            const int idx = aI*2 + l;
#pragma unroll
            for (int q = 0; q < 4; ++q) {
                float phi = pp[l*12 + q*3 + 0];
                float tht = pp[l*12 + q*3 + 1];
                float omg = pp[l*12 + q*3 + 2];
                float st, ct; sincosf(0.5f*tht, &st, &ct);
                float sA, cA, sB, cB;
                sincosf(0.5f*(phi + omg), &sA, &cA);
                sincosf(0.5f*(phi - omg), &sB, &cB);
                C2 u00 = {  cA*ct, -sA*ct };
                C2 u01 = { -cB*st, -sB*st };
                if (q == 0) {
                    Ls[idx][0]=rfl(u00.r); Ls[idx][1]=rfl(u00.i);
                    Ls[idx][2]=rfl(u01.r); Ls[idx][3]=rfl(u01.i);
                } else {
                    float zq = (q == 1) ? z1f : (q == 2) ? z2f : z3f;
                    LUr[idx][q-1] = rfl(u00.r);
                    LWi[idx][q-1] = rfl(u01.i);
                    LvA[idx][q-1] = zq * u00.i;
                    LvB[idx][q-1] = zq * u01.r;
                }
            }
        }
    }

    // ---- KAN poly coeffs (lane 'sub' = input dim); REVC convention folded in
    float Q0[7], Q1[7], Q2[7], Q3[7], BW[7];
#pragma unroll
    for (int r = 0; r < 7; ++r) {
        float sw0 = ksw[r*16 + sub*4 + 0], sw1 = ksw[r*16 + sub*4 + 1];
        float sw2 = ksw[r*16 + sub*4 + 2], sw3 = ksw[r*16 + sub*4 + 3];
        const float f = REVC / 48.0f;
        Q0[r] = f * (sw0 + 23.f*sw1 + 23.f*sw2 + sw3);
        Q1[r] = f * (-3.f*sw0 - 15.f*sw1 + 15.f*sw2 + 3.f*sw3);
        Q2[r] = f * (3.f*sw0 - 3.f*sw1 - 3.f*sw2 + 3.f*sw3);
        Q3[r] = f * (-sw0 + 3.f*sw1 - 3.f*sw2 + sw3);
        BW[r] = REVC * kbw[r*4 + sub];
    }

    float ha[7];  // revolutions, -0.5 folded
#pragma unroll
    for (int k = 0; k < 7; ++k) ha[k] = REVC * initial_t[e*7 + k];

    const float4* inp4 = (const float4*)inputs;
    const long basei = (long)e * S;
    float4 xc = inp4[basei];

    const float NQPI = -0.7853981633974483f;   // -pi/4
    float xk = 0.f;

#pragma unroll 1
    for (int t = 0; t < S; ++t) {
        const int tn = (t + 1 < S) ? t + 1 : S - 1;
        float4 xn = inp4[basei + tn];

        C2 a0, a1;

        // ---- fm(hidden) on |0000>: amp = e^{i*2pi*sig}
        {
            float base = ha[1]*z1f;
            base = fmaf(ha[2], z2f, base);
            base = fmaf(ha[3], z3f, base);
            base = fmaf(ha[5], z12, base);
            base = fmaf(ha[6], z23, base);
            float w = fmaf(ha[4], z1f, ha[0]);
            fsincos(base + w, &a0.i, &a0.r);
            fsincos(base - w, &a1.i, &a1.r);
        }

        // ---- ansatz(p1) then fm(x) then ansatz(p2): two 2-layer loops.
        // CNOT(3,0) of layers 2 and 4 (li==1) is FOLDED into the consumer
        // (fm H-q0 fixup / measurement d-sign), not applied here.
#pragma unroll
        for (int half = 0; half < 2; ++half) {
#pragma unroll
            for (int li = 0; li < 2; ++li) {
                const int l = half*2 + li;
                rot_q0(a0, a1, Ls[l][0], Ls[l][1], Ls[l][2], Ls[l][3]);
                { float pr = ror8(a0.r), pi = ror8(a0.i);
                  float qr = ror8(a1.r), qi = ror8(a1.i);
                  rot_d(a0, pr, pi, LUr[l][0], LWi[l][0], LvA[l][0], LvB[l][0]);
                  rot_d(a1, qr, qi, LUr[l][0], LWi[l][0], LvA[l][0], LvB[l][0]); }
                { float pr = lx1(a0.r), pi = lx1(a0.i);
                  float qr = lx1(a1.r), qi = lx1(a1.i);
                  rot_d(a0, pr, pi, LUr[l][1], LWi[l][1], LvA[l][1], LvB[l][1]);
                  rot_d(a1, qr, qi, LUr[l][1], LWi[l][1], LvA[l][1], LvB[l][1]); }
                { float pr = lx2(a0.r), pi = lx2(a0.i);
                  float qr = lx2(a1.r), qi = lx2(a1.i);
                  rot_d(a0, pr, pi, LUr[l][2], LWi[l][2], LvA[l][2], LvB[l][2]);
                  rot_d(a1, qr, qi, LUr[l][2], LWi[l][2], LvA[l][2], LvB[l][2]); }
                // CNOT(0,1)
                a1.r = ror8(a1.r); a1.i = ror8(a1.i);
                // CNOT(1,2) o CNOT(2,3): b1=0 -> 0x6C; b1=1 -> 0x39
                { float vA, vB;
                  vA = qperm<0x6C>(a0.r); vB = qperm<0x39>(a0.r); a0.r = b1 ? vB : vA;
                  vA = qperm<0x6C>(a0.i); vB = qperm<0x39>(a0.i); a0.i = b1 ? vB : vA;
                  vA = qperm<0x6C>(a1.r); vB = qperm<0x39>(a1.r); a1.r = b1 ? vB : vA;
                  vA = qperm<0x6C>(a1.i); vB = qperm<0x39>(a1.i); a1.i = b1 ? vB : vA; }
                // CNOT(3,0): only for li==0 layers; li==1 folded into consumer
                if (li == 0) {
                    float t0r = b3 ? a1.r : a0.r, t0i = b3 ? a1.i : a0.i;
                    float t1r = b3 ? a0.r : a1.r, t1i = b3 ? a0.i : a1.i;
                    a0.r = t0r; a0.i = t0i; a1.r = t1r; a1.i = t1i;
                }
            }
            if (half == 0) {
                // ---- fm(x_embed): H^{x4} (unscaled) + diag phase (revolutions)
                float he[7];
                float hx0 = REVC*xc.x, hx1 = REVC*xc.y, hx2 = REVC*xc.z, hx3 = REVC*xc.w;
                he[0]=hx0; he[1]=hx1; he[2]=hx2; he[3]=hx3;
                // (pi-x_a)(pi-x_b) * REVC = -pi/4 * (1+4hx_a)(1+4hx_b)
                float u0 = fmaf(4.f, hx0, 1.f);
                float u1 = fmaf(4.f, hx1, 1.f);
                float u2 = fmaf(4.f, hx2, 1.f);
                float u3 = fmaf(4.f, hx3, 1.f);
                he[4] = NQPI * (u0*u1);
                he[5] = NQPI * (u1*u2);
                he[6] = NQPI * (u2*u3);

                // H q0 + folded CNOT(3,0) of layer 2: (sum,diff) then a1 *= z3f
                C2 n0 = { a0.r + a1.r, a0.i + a1.i };
                C2 n1 = { a0.r - a1.r, a0.i - a1.i };
                a0 = n0;
                a1.r = n1.r * z3f; a1.i = n1.i * z3f;
                { float pr = ror8(a0.r), pi = ror8(a0.i);
                  a0.r = fmaf(z1f, a0.r, pr); a0.i = fmaf(z1f, a0.i, pi);
                  float qr = ror8(a1.r), qi = ror8(a1.i);
                  a1.r = fmaf(z1f, a1.r, qr); a1.i = fmaf(z1f, a1.i, qi); }
                { float pr = lx1(a0.r), pi = lx1(a0.i);
                  a0.r = fmaf(z2f, a0.r, pr); a0.i = fmaf(z2f, a0.i, pi);
                  float qr = lx1(a1.r), qi = lx1(a1.i);
                  a1.r = fmaf(z2f, a1.r, qr); a1.i = fmaf(z2f, a1.i, qi); }
                { float pr = lx2(a0.r), pi = lx2(a0.i);
                  a0.r = fmaf(z3f, a0.r, pr); a0.i = fmaf(z3f, a0.i, pi);
                  float qr = lx2(a1.r), qi = lx2(a1.i);
                  a1.r = fmaf(z3f, a1.r, qr); a1.i = fmaf(z3f, a1.i, qi); }
                float base = he[1]*z1f;
                base = fmaf(he[2], z2f, base);
                base = fmaf(he[3], z3f, base);
                base = fmaf(he[5], z12, base);
                base = fmaf(he[6], z23, base);
                float w = fmaf(he[4], z1f, he[0]);
                float s0, c0, s1, c1;
                fsincos(base + w, &s0, &c0);
                fsincos(base - w, &s1, &c1);
                float nr0 = a0.r*c0 - a0.i*s0, ni0 = a0.i*c0 + a0.r*s0;
                float nr1 = a1.r*c1 - a1.i*s1, ni1 = a1.i*c1 + a1.r*s1;
                a0.r = nr0; a0.i = ni0; a1.r = nr1; a1.i = ni1;
            }
        }

        // ---- measurement (probs carry x256). Layer-4 CNOT(3,0) folded: d *= z3f
        float p0 = fmaf(a0.i, a0.i, a0.r*a0.r);
        float pq = fmaf(a1.i, a1.i, a1.r*a1.r);
        float s  = p0 + pq;
        float d  = (p0 - pq) * z3f;
        float ea = d + lx1(d);   ea += lx2(ea); ea += ror8(ea);   // 256*ev0 (all lanes)
        float t1 = z1f * s;
        float eb = t1 + lx1(t1); eb += lx2(eb); eb += ror8(eb);   // 256*ev1 (all lanes)
        float u = k0c * s;                                        // twisted chain:
        u = fmaf(sg1, lx1(u), u);                                 //  sub2 -> 256*ev2
        u += lx2(u);                                              //  sub3 -> 256*ev3
        u += ror8(u);
        xk = b3 ? u : (b2 ? eb : ea);
        xk *= (1.0f/256.0f);

        // ---- KAN: lane sub = dim; quad-reduce sums the 4 dims.
        // silu via native exp2/rcp: sg = 1/(1+e^-x), e^-x = exp2(-x*log2e)
        float eneg = __builtin_amdgcn_exp2f(xk * -1.44269504088896f);
        float silu = xk * __builtin_amdgcn_rcpf(1.0f + eneg);
#pragma unroll
        for (int r = 0; r < 7; ++r) {
            float o = fmaf(Q3[r], xk, Q2[r]);
            o = fmaf(o, xk, Q1[r]);
            o = fmaf(o, xk, Q0[r]);
            o = fmaf(BW[r], silu, o);
            o += lx1(o); o += lx2(o);
            ha[r] = o;
        }

        xc = xn;
    }

    // ---- classifier head: quad lanes hold ev0..ev3
    float ev1 = qperm<0x55>(xk);
    float ev2 = qperm<0xAA>(xk);
    float ev3 = qperm<0xFF>(xk);
    if (sub == 0 && !b1) {
        float acc = cb2[0];
#pragma unroll
        for (int i = 0; i < 16; ++i) {
            float h = cb1[i] + w1[i*4+0]*xk + w1[i*4+1]*ev1
                    + w1[i*4+2]*ev2 + w1[i*4+3]*ev3;
            h = fmaxf(h, 0.0f);
            acc += w2[i]*h;
        }
        out[e] = acc;
    }
}

extern "C" void kernel_launch(void* const* d_in, const int* in_sizes, int n_in,
                              void* d_out, int out_size, void* d_ws, size_t ws_size,
                              hipStream_t stream) {
    const float* inputs    = (const float*)d_in[0];
    const float* initial_t = (const float*)d_in[1];
    const float* p1        = (const float*)d_in[2];
    const float* p2        = (const float*)d_in[3];
    const float* kbw       = (const float*)d_in[4];
    const float* ksw       = (const float*)d_in[5];
    const float* w1        = (const float*)d_in[6];
    const float* cb1       = (const float*)d_in[7];
    const float* w2        = (const float*)d_in[8];
    const float* cb2       = (const float*)d_in[9];

    const int B = in_sizes[1] / 7;            // 16384
    const int S = in_sizes[0] / (B * 4);      // 256

    const int threads = B * 8;                // 8 lanes per batch element
    const int block = 256;
    const int grid = (threads + block - 1) / block;   // 512 blocks -> 8 waves/CU

    qrnn_kernel<<<grid, block, 0, stream>>>(inputs, initial_t, p1, p2, kbw, ksw,
                                            w1, cb1, w2, cb2, (float*)d_out, B, S);
}

// Round 5
// 453.215 us; speedup vs baseline: 1.4283x; 1.2345x over previous
//
#include <hip/hip_runtime.h>
#include <math.h>

#define DEV static __device__ __forceinline__

typedef float v2 __attribute__((ext_vector_type(2)));

// DPP helpers — all cross-lane traffic is full-rate VALU DPP (no LDS pipe).
template<int CTRL>
DEV float qperm(float x) {
    return __int_as_float(__builtin_amdgcn_mov_dpp(__float_as_int(x), CTRL, 0xF, 0xF, true));
}
DEV float lx1(float v)  { return qperm<0xB1>(v); }  // quad: xor lane bit0 (qubit2)
DEV float lx2(float v)  { return qperm<0x4E>(v); }  // quad: xor lane bit1 (qubit3)
DEV float ror8(float v) { return qperm<0x128>(v); } // row_ror:8 = xor lane bit3 (qubit1)
DEV float rfl(float x)  { return __int_as_float(__builtin_amdgcn_readfirstlane(__float_as_int(x))); }

template<int CTRL>
DEV v2 qpermv(v2 a) { return (v2){qperm<CTRL>(a.x), qperm<CTRL>(a.y)}; }

DEV v2 vswap(v2 a)  { return __builtin_shufflevector(a, a, 1, 0); }
DEV v2 vsplat(float f) { return (v2){f, f}; }
DEV v2 vfma(v2 a, v2 b, v2 c) { return __builtin_elementwise_fma(a, b, c); }

// Rot on local qubit0 (packed): x' = S x + T y ; y' = -conj(T) x + conj(S) y
// Sr,Tr,nTr = scalars (SGPR); Sin=(-Si,Si), Tin=(-Ti,Ti) = VGPR pairs.
DEV void rot_q0v(v2& x, v2& y, float Sr, float Tr, float nTr, v2 Sin, v2 Tin) {
    v2 sx = vswap(x), sy = vswap(y);
    v2 nx = x * Sr;
    nx = vfma(sx, Sin, nx);
    nx = vfma(y, vsplat(Tr), nx);
    nx = vfma(sy, Tin, nx);
    v2 ny = y * Sr;
    ny = vfma(sy, vswap(Sin), ny);
    ny = vfma(x, vsplat(nTr), ny);
    ny = vfma(sx, Tin, ny);
    x = nx; y = ny;
}

// Rot on a lane-distributed qubit (packed): coeffs {Ur(SGPR), An=(-vAI,vAI)(VGPR),
// Br=vBR(VGPR), Wn=(-Wi,Wi)(VGPR)}; p = partner amp (via DPP).
DEV v2 rot_dv(v2 a, v2 p, float Ur, v2 An, float Br, v2 Wn) {
    v2 n = a * Ur;
    n = vfma(vswap(a), An, n);
    n = vfma(p, vsplat(Br), n);
    n = vfma(vswap(p), Wn, n);
    return n;
}

// Cheap sincos in REVOLUTIONS: v_fract + v_sin + v_cos.
DEV void fsincos(float rev, float* s, float* c) {
    float f = __builtin_amdgcn_fractf(rev);
    *s = __builtin_amdgcn_sinf(f);
    *c = __builtin_amdgcn_cosf(f);
}

__global__ __launch_bounds__(256, 2)
void qrnn_kernel(const float* __restrict__ inputs, const float* __restrict__ initial_t,
                 const float* __restrict__ p1, const float* __restrict__ p2,
                 const float* __restrict__ kbw, const float* __restrict__ ksw,
                 const float* __restrict__ w1, const float* __restrict__ cb1,
                 const float* __restrict__ w2, const float* __restrict__ cb2,
                 float* __restrict__ out, int B, int S)
{
    // 8 lanes/element: lane bit0->qubit2, bit1->qubit3, bit3->qubit1; bit2 = element sel.
    const int tid    = blockIdx.x * blockDim.x + threadIdx.x;
    const int lane16 = threadIdx.x & 15;
    const int e      = (tid >> 4) * 2 + ((lane16 >> 2) & 1);
    const int sub    = lane16 & 3;
    const bool b1    = ((lane16 >> 3) & 1) != 0;
    if (e >= B) return;
    const bool b2 = (sub & 1) != 0, b3 = (sub & 2) != 0;
    const float z2f = b2 ? -1.f : 1.f;
    const float z3f = b3 ? -1.f : 1.f;
    const float z1f = b1 ? -1.f : 1.f;
    const float z12 = z1f * z2f, z23 = z2f * z3f;
    const float z123 = z1f * z23;
    const bool is0 = (sub == 0), is1 = (sub == 1);

    // Angles carried in REVOLUTIONS, -0.5 half-angle folded: stored = -rad/(4*pi).
    const float REVC = -0.07957747154594767f;   // -1/(4*pi)

    // ---- one-time: 16 Rot matrices (input-constant)
    float Sr[4], Tr[4], nTr[4];    // qubit0 scalars (SGPR via rfl)
    v2    Sin[4], Tin[4];          // qubit0 sign-pairs
    float Ur[4][3], Br[4][3];      // distributed qubits: SGPR scalar + lane VGPR
    v2    An[4][3], Wn[4][3];      // distributed qubits: packed sign-pairs
    const float* PP[2] = { p1, p2 };
#pragma unroll
    for (int aI = 0; aI < 2; ++aI) {
        const float* pp = PP[aI];
#pragma unroll
        for (int l = 0; l < 2; ++l) {
            const int idx = aI*2 + l;
#pragma unroll
            for (int q = 0; q < 4; ++q) {
                float phi = pp[l*12 + q*3 + 0];
                float tht = pp[l*12 + q*3 + 1];
                float omg = pp[l*12 + q*3 + 2];
                float st, ct; sincosf(0.5f*tht, &st, &ct);
                float sA, cA, sB, cB;
                sincosf(0.5f*(phi + omg), &sA, &cA);
                sincosf(0.5f*(phi - omg), &sB, &cB);
                float u00r =  cA*ct, u00i = -sA*ct;
                float u01r = -cB*st, u01i = -sB*st;
                if (q == 0) {
                    Sr[idx] = rfl(u00r); Tr[idx] = rfl(u01r); nTr[idx] = rfl(-u01r);
                    float Si = rfl(u00i), Ti = rfl(u01i);
                    Sin[idx] = (v2){-Si, Si};
                    Tin[idx] = (v2){-Ti, Ti};
                } else {
                    float zq = (q == 1) ? z1f : (q == 2) ? z2f : z3f;
                    Ur[idx][q-1] = rfl(u00r);
                    float Wi = rfl(u01i);
                    Wn[idx][q-1] = (v2){-Wi, Wi};
                    float vAI = zq * u00i;
                    An[idx][q-1] = (v2){-vAI, vAI};
                    Br[idx][q-1] = zq * u01r;
                }
            }
        }
    }

    // ---- KAN: spline over [-1,1] collapses to cubics; weights + REVC folded.
    // Outputs paired (0,4),(1,2),(3,6), scalar 5 to match angle usage.
    float kQ0[7], kQ1[7], kQ2[7], kQ3[7], kBW[7];
#pragma unroll
    for (int r = 0; r < 7; ++r) {
        float sw0 = ksw[r*16 + sub*4 + 0], sw1 = ksw[r*16 + sub*4 + 1];
        float sw2 = ksw[r*16 + sub*4 + 2], sw3 = ksw[r*16 + sub*4 + 3];
        const float f = REVC / 48.0f;
        kQ0[r] = f * (sw0 + 23.f*sw1 + 23.f*sw2 + sw3);
        kQ1[r] = f * (-3.f*sw0 - 15.f*sw1 + 15.f*sw2 + 3.f*sw3);
        kQ2[r] = f * (3.f*sw0 - 3.f*sw1 - 3.f*sw2 + 3.f*sw3);
        kQ3[r] = f * (-sw0 + 3.f*sw1 - 3.f*sw2 + sw3);
        kBW[r] = REVC * kbw[r*4 + sub];
    }
    const int pr0[3] = {0, 1, 3}, pr1[3] = {4, 2, 6};
    v2 Q0p[3], Q1p[3], Q2p[3], Q3p[3], BWp[3];
#pragma unroll
    for (int j = 0; j < 3; ++j) {
        Q0p[j] = (v2){kQ0[pr0[j]], kQ0[pr1[j]]};
        Q1p[j] = (v2){kQ1[pr0[j]], kQ1[pr1[j]]};
        Q2p[j] = (v2){kQ2[pr0[j]], kQ2[pr1[j]]};
        Q3p[j] = (v2){kQ3[pr0[j]], kQ3[pr1[j]]};
        BWp[j] = (v2){kBW[pr0[j]], kBW[pr1[j]]};
    }

    // hidden state: pairs h04=(ha0,ha4), h12=(ha1,ha2), h36=(ha3,ha6), scalar h5
    v2 h04 = (v2){REVC*initial_t[e*7+0], REVC*initial_t[e*7+4]};
    v2 h12 = (v2){REVC*initial_t[e*7+1], REVC*initial_t[e*7+2]};
    v2 h36 = (v2){REVC*initial_t[e*7+3], REVC*initial_t[e*7+6]};
    float h5 = REVC*initial_t[e*7+5];

    const float4* inp4 = (const float4*)inputs;
    const long basei = (long)e * S;
    float4 xc = inp4[basei];

    const float NQPI = -0.7853981633974483f;   // -pi/4
    float xk = 0.f;

#pragma unroll 1
    for (int t = 0; t < S; ++t) {
        const int tn = (t + 1 < S) ? t + 1 : S - 1;
        float4 xn = inp4[basei + tn];

        v2 a0, a1;

        // ---- fm(hidden) on |0000>: amp = e^{i*2pi*sig}
        {
            float base = h12.x * z1f;
            base = fmaf(h12.y, z2f, base);
            base = fmaf(h36.x, z3f, base);
            base = fmaf(h5,   z12, base);
            base = fmaf(h36.y, z23, base);
            float w = fmaf(h04.y, z1f, h04.x);
            float s0, c0, s1, c1;
            fsincos(base + w, &s0, &c0);
            fsincos(base - w, &s1, &c1);
            a0 = (v2){c0, s0};
            a1 = (v2){c1, s1};
        }

        // ---- ansatz(p1), fm(x), ansatz(p2).
        // Layer-2 CNOT(3,0) folded into fm_x H-q0; layer-4 ring FULLY folded
        // into measurement masks (ring is a GF2 basis perm => Walsh relabel).
#pragma unroll
        for (int half = 0; half < 2; ++half) {
#pragma unroll
            for (int li = 0; li < 2; ++li) {
                const int l = half*2 + li;
                rot_q0v(a0, a1, Sr[l], Tr[l], nTr[l], Sin[l], Tin[l]);
                { v2 q0 = qpermv<0x128>(a0), q1 = qpermv<0x128>(a1);  // qubit1
                  a0 = rot_dv(a0, q0, Ur[l][0], An[l][0], Br[l][0], Wn[l][0]);
                  a1 = rot_dv(a1, q1, Ur[l][0], An[l][0], Br[l][0], Wn[l][0]); }
                { v2 q0 = qpermv<0xB1>(a0), q1 = qpermv<0xB1>(a1);    // qubit2
                  a0 = rot_dv(a0, q0, Ur[l][1], An[l][1], Br[l][1], Wn[l][1]);
                  a1 = rot_dv(a1, q1, Ur[l][1], An[l][1], Br[l][1], Wn[l][1]); }
                { v2 q0 = qpermv<0x4E>(a0), q1 = qpermv<0x4E>(a1);    // qubit3
                  a0 = rot_dv(a0, q0, Ur[l][2], An[l][2], Br[l][2], Wn[l][2]);
                  a1 = rot_dv(a1, q1, Ur[l][2], An[l][2], Br[l][2], Wn[l][2]); }
                if (l < 3) {
                    // CNOT(0,1)
                    a1 = qpermv<0x128>(a1);
                    // CNOT(1,2) o CNOT(2,3): b1=0 -> [0,3,2,1]; b1=1 -> [1,2,3,0]
                    { float vA, vB;
                      vA = qperm<0x6C>(a0.x); vB = qperm<0x39>(a0.x); a0.x = b1 ? vB : vA;
                      vA = qperm<0x6C>(a0.y); vB = qperm<0x39>(a0.y); a0.y = b1 ? vB : vA;
                      vA = qperm<0x6C>(a1.x); vB = qperm<0x39>(a1.x); a1.x = b1 ? vB : vA;
                      vA = qperm<0x6C>(a1.y); vB = qperm<0x39>(a1.y); a1.y = b1 ? vB : vA; }
                    // CNOT(3,0): layers 1,3 only (layer 2's folded into fm_x)
                    if (li == 0) {
                        v2 t0 = b3 ? a1 : a0;
                        v2 t1 = b3 ? a0 : a1;
                        a0 = t0; a1 = t1;
                    }
                }
            }
            if (half == 0) {
                // ---- fm(x_embed): H^{x4} (unscaled) + diag phase (revolutions)
                float hx0 = REVC*xc.x, hx1 = REVC*xc.y, hx2 = REVC*xc.z, hx3 = REVC*xc.w;
                float u0 = fmaf(4.f, hx0, 1.f);
                float u1 = fmaf(4.f, hx1, 1.f);
                float u2 = fmaf(4.f, hx2, 1.f);
                float u3 = fmaf(4.f, hx3, 1.f);
                float he4 = NQPI * (u0*u1);
                float he5 = NQPI * (u1*u2);
                float he6 = NQPI * (u2*u3);

                // H q0 + folded layer-2 CNOT(3,0): diff scaled by z3f
                v2 n0 = a0 + a1;
                v2 n1 = (a0 - a1) * z3f;
                a0 = n0; a1 = n1;
                { v2 q0 = qpermv<0x128>(a0), q1 = qpermv<0x128>(a1);  // H qubit1
                  a0 = vfma(a0, vsplat(z1f), q0);
                  a1 = vfma(a1, vsplat(z1f), q1); }
                { v2 q0 = qpermv<0xB1>(a0), q1 = qpermv<0xB1>(a1);    // H qubit2
                  a0 = vfma(a0, vsplat(z2f), q0);
                  a1 = vfma(a1, vsplat(z2f), q1); }
                { v2 q0 = qpermv<0x4E>(a0), q1 = qpermv<0x4E>(a1);    // H qubit3
                  a0 = vfma(a0, vsplat(z3f), q0);
                  a1 = vfma(a1, vsplat(z3f), q1); }
                float base = hx1 * z1f;
                base = fmaf(hx2, z2f, base);
                base = fmaf(hx3, z3f, base);
                base = fmaf(he5, z12, base);
                base = fmaf(he6, z23, base);
                float w = fmaf(he4, z1f, hx0);
                float s0, c0, s1, c1;
                fsincos(base + w, &s0, &c0);
                fsincos(base - w, &s1, &c1);
                v2 sn0 = (v2){-s0, s0};
                v2 sn1 = (v2){-s1, s1};
                a0 = vfma(vswap(a0), sn0, a0 * c0);
                a1 = vfma(vswap(a1), sn1, a1 * c1);
            }
        }

        // ---- measurement with layer-4 ring folded into Walsh masks:
        // ev0 = sum z1z2z3 (p0+p1); ev1 = sum z1 (p0-p1);
        // ev2 = sum z1z2 (p0-p1);   ev3 = sum z1z2z3 (p0-p1).   (probs carry x256)
        v2 m0 = a0 * a0, m1 = a1 * a1;
        float pa = m0.x + m0.y;
        float pb = m1.x + m1.y;
        float s  = pa + pb;
        float dl = pa - pb;
        float u0m = z1f * dl;
        float r3 = u0m + ror8(u0m);                 // sum over bit3 (qubit1 in base)
        float rA = r3 + lx1(r3); rA += lx2(rA);     // ev1 at every lane
        float rB = r3 - lx1(r3);                    // z2-weighted (sign slop z2f)
        float rC = fmaf(z2f, lx2(rB), rB);          // sub2 -> ev2 ; sub3 -> ev3 (exact)
        float vy = z123 * s;
        vy += ror8(vy); vy += lx1(vy); vy += lx2(vy);  // ev0 at every lane
        float pre = is0 ? vy : (is1 ? rA : rC);
        xk = pre * (1.0f/256.0f);

        // ---- KAN (packed pairs): lane sub = input dim; quad-reduce sums dims
        float eneg = __builtin_amdgcn_exp2f(xk * -1.44269504088896f);
        float silu = xk * __builtin_amdgcn_rcpf(1.0f + eneg);
        v2 xs = vsplat(xk), ss = vsplat(silu);
        v2 op[3];
#pragma unroll
        for (int j = 0; j < 3; ++j) {
            v2 o = vfma(Q3p[j], xs, Q2p[j]);
            o = vfma(o, xs, Q1p[j]);
            o = vfma(o, xs, Q0p[j]);
            o = vfma(BWp[j], ss, o);
            o = o + (v2){lx1(o.x), lx1(o.y)};
            o = o + (v2){lx2(o.x), lx2(o.y)};
            op[j] = o;
        }
        {   // scalar r=5
            float o = fmaf(kQ3[5], xk, kQ2[5]);
            o = fmaf(o, xk, kQ1[5]);
            o = fmaf(o, xk, kQ0[5]);
            o = fmaf(kBW[5], silu, o);
            o += lx1(o); o += lx2(o);
            h5 = o;
        }
        h04 = op[0]; h12 = op[1]; h36 = op[2];

        xc = xn;
    }

    // ---- classifier head: quad lanes hold ev0..ev3
    float ev1 = qperm<0x55>(xk);
    float ev2 = qperm<0xAA>(xk);
    float ev3 = qperm<0xFF>(xk);
    if (sub == 0 && !b1) {
        float acc = cb2[0];
#pragma unroll
        for (int i = 0; i < 16; ++i) {
            float h = cb1[i] + w1[i*4+0]*xk + w1[i*4+1]*ev1
                    + w1[i*4+2]*ev2 + w1[i*4+3]*ev3;
            h = fmaxf(h, 0.0f);
            acc += w2[i]*h;
        }
        out[e] = acc;
    }
}

extern "C" void kernel_launch(void* const* d_in, const int* in_sizes, int n_in,
                              void* d_out, int out_size, void* d_ws, size_t ws_size,
                              hipStream_t stream) {
    const float* inputs    = (const float*)d_in[0];
    const float* initial_t = (const float*)d_in[1];
    const float* p1        = (const float*)d_in[2];
    const float* p2        = (const float*)d_in[3];
    const float* kbw       = (const float*)d_in[4];
    const float* ksw       = (const float*)d_in[5];
    const float* w1        = (const float*)d_in[6];
    const float* cb1       = (const float*)d_in[7];
    const float* w2        = (const float*)d_in[8];
    const float* cb2       = (const float*)d_in[9];

    const int B = in_sizes[1] / 7;            // 16384
    const int S = in_sizes[0] / (B * 4);      // 256

    const int threads = B * 8;                // 8 lanes per batch element
    const int block = 256;
    const int grid = (threads + block - 1) / block;   // 512 blocks -> 8 waves/CU

    qrnn_kernel<<<grid, block, 0, stream>>>(inputs, initial_t, p1, p2, kbw, ksw,
                                            w1, cb1, w2, cb2, (float*)d_out, B, S);
}

// Round 6
// 449.819 us; speedup vs baseline: 1.4391x; 1.0075x over previous
//
#include <hip/hip_runtime.h>
#include <math.h>

#define DEV static __device__ __forceinline__

typedef float v2 __attribute__((ext_vector_type(2)));

// DPP helpers — all cross-lane traffic is full-rate VALU DPP (no LDS pipe).
template<int CTRL>
DEV float qperm(float x) {
    return __int_as_float(__builtin_amdgcn_mov_dpp(__float_as_int(x), CTRL, 0xF, 0xF, true));
}
DEV float lx1(float v)  { return qperm<0xB1>(v); }  // quad: xor lane bit0 (qubit2)
DEV float lx2(float v)  { return qperm<0x4E>(v); }  // quad: xor lane bit1 (qubit3)
DEV float ror8(float v) { return qperm<0x128>(v); } // row_ror:8 = xor lane bit3 (qubit1)
DEV float rfl(float x)  { return __int_as_float(__builtin_amdgcn_readfirstlane(__float_as_int(x))); }

template<int CTRL>
DEV v2 qpermv(v2 a) { return (v2){qperm<CTRL>(a.x), qperm<CTRL>(a.y)}; }

DEV v2 vswap(v2 a)  { return __builtin_shufflevector(a, a, 1, 0); }
DEV v2 vsplat(float f) { return (v2){f, f}; }
DEV v2 vfma(v2 a, v2 b, v2 c) { return __builtin_elementwise_fma(a, b, c); }

// Rot on local qubit0 (packed): x' = S x + T y ; y' = -conj(T) x + conj(S) y
DEV void rot_q0v(v2& x, v2& y, float Sr, float Tr, float nTr, v2 Sin, v2 Tin) {
    v2 sx = vswap(x), sy = vswap(y);
    v2 nx = x * Sr;
    nx = vfma(sx, Sin, nx);
    nx = vfma(y, vsplat(Tr), nx);
    nx = vfma(sy, Tin, nx);
    v2 ny = y * Sr;
    ny = vfma(sy, vswap(Sin), ny);
    ny = vfma(x, vsplat(nTr), ny);
    ny = vfma(sx, Tin, ny);
    x = nx; y = ny;
}

// Rot on a lane-distributed qubit (packed); p = partner amp (via DPP).
DEV v2 rot_dv(v2 a, v2 p, float Ur, v2 An, float Br, v2 Wn) {
    v2 n = a * Ur;
    n = vfma(vswap(a), An, n);
    n = vfma(p, vsplat(Br), n);
    n = vfma(vswap(p), Wn, n);
    return n;
}

// Cheap sincos in REVOLUTIONS: v_fract + v_sin + v_cos.
DEV void fsincos(float rev, float* s, float* c) {
    float f = __builtin_amdgcn_fractf(rev);
    *s = __builtin_amdgcn_sinf(f);
    *c = __builtin_amdgcn_cosf(f);
}

__global__ __launch_bounds__(256, 1)
void qrnn_kernel(const float* __restrict__ inputs, const float* __restrict__ initial_t,
                 const float* __restrict__ p1, const float* __restrict__ p2,
                 const float* __restrict__ kbw, const float* __restrict__ ksw,
                 const float* __restrict__ w1, const float* __restrict__ cb1,
                 const float* __restrict__ w2, const float* __restrict__ cb2,
                 float* __restrict__ out, int B, int S)
{
    // 8 lanes/slot, TWO elements per thread (eA, eB=eA+B/2) for 2-way ILP.
    // lane bit0->qubit2, bit1->qubit3, bit3->qubit1; bit2 = slot select.
    const int tid    = blockIdx.x * blockDim.x + threadIdx.x;
    const int lane16 = threadIdx.x & 15;
    const int eA     = (tid >> 4) * 2 + ((lane16 >> 2) & 1);
    const int halfB  = B >> 1;
    if (eA >= halfB) return;
    const int eB     = eA + halfB;
    const int sub    = lane16 & 3;
    const bool b1    = ((lane16 >> 3) & 1) != 0;
    const bool b2 = (sub & 1) != 0, b3 = (sub & 2) != 0;
    const float z2f = b2 ? -1.f : 1.f;
    const float z3f = b3 ? -1.f : 1.f;
    const float z1f = b1 ? -1.f : 1.f;
    const float z12 = z1f * z2f, z23 = z2f * z3f;
    const float z123 = z1f * z23;
    const bool is0 = (sub == 0), is1 = (sub == 1);

    // Angles in REVOLUTIONS with -0.5 half-angle folded: stored = -rad/(4*pi).
    const float REVC = -0.07957747154594767f;   // -1/(4*pi)

    // ---- one-time: 16 Rot matrices (input-constant, element-independent)
    float Sr[4], Tr[4], nTr[4];
    v2    Sin[4], Tin[4];
    float Ur[4][3], Br[4][3];
    v2    An[4][3], Wn[4][3];
    const float* PP[2] = { p1, p2 };
#pragma unroll
    for (int aI = 0; aI < 2; ++aI) {
        const float* pp = PP[aI];
#pragma unroll
        for (int l = 0; l < 2; ++l) {
            const int idx = aI*2 + l;
#pragma unroll
            for (int q = 0; q < 4; ++q) {
                float phi = pp[l*12 + q*3 + 0];
                float tht = pp[l*12 + q*3 + 1];
                float omg = pp[l*12 + q*3 + 2];
                float st, ct; sincosf(0.5f*tht, &st, &ct);
                float sA, cA, sB, cB;
                sincosf(0.5f*(phi + omg), &sA, &cA);
                sincosf(0.5f*(phi - omg), &sB, &cB);
                float u00r =  cA*ct, u00i = -sA*ct;
                float u01r = -cB*st, u01i = -sB*st;
                if (q == 0) {
                    Sr[idx] = rfl(u00r); Tr[idx] = rfl(u01r); nTr[idx] = rfl(-u01r);
                    float Si = rfl(u00i), Ti = rfl(u01i);
                    Sin[idx] = (v2){-Si, Si};
                    Tin[idx] = (v2){-Ti, Ti};
                } else {
                    float zq = (q == 1) ? z1f : (q == 2) ? z2f : z3f;
                    Ur[idx][q-1] = rfl(u00r);
                    float Wi = rfl(u01i);
                    Wn[idx][q-1] = (v2){-Wi, Wi};
                    float vAI = zq * u00i;
                    An[idx][q-1] = (v2){-vAI, vAI};
                    Br[idx][q-1] = zq * u01r;
                }
            }
        }
    }

    // ---- KAN cubic coeffs (lane 'sub' = input dim); REVC folded.
    float kQ0[7], kQ1[7], kQ2[7], kQ3[7], kBW[7];
#pragma unroll
    for (int r = 0; r < 7; ++r) {
        float sw0 = ksw[r*16 + sub*4 + 0], sw1 = ksw[r*16 + sub*4 + 1];
        float sw2 = ksw[r*16 + sub*4 + 2], sw3 = ksw[r*16 + sub*4 + 3];
        const float f = REVC / 48.0f;
        kQ0[r] = f * (sw0 + 23.f*sw1 + 23.f*sw2 + sw3);
        kQ1[r] = f * (-3.f*sw0 - 15.f*sw1 + 15.f*sw2 + 3.f*sw3);
        kQ2[r] = f * (3.f*sw0 - 3.f*sw1 - 3.f*sw2 + 3.f*sw3);
        kQ3[r] = f * (-sw0 + 3.f*sw1 - 3.f*sw2 + sw3);
        kBW[r] = REVC * kbw[r*4 + sub];
    }
    const int pr0[3] = {0, 1, 3}, pr1[3] = {4, 2, 6};
    v2 Q0p[3], Q1p[3], Q2p[3], Q3p[3], BWp[3];
#pragma unroll
    for (int j = 0; j < 3; ++j) {
        Q0p[j] = (v2){kQ0[pr0[j]], kQ0[pr1[j]]};
        Q1p[j] = (v2){kQ1[pr0[j]], kQ1[pr1[j]]};
        Q2p[j] = (v2){kQ2[pr0[j]], kQ2[pr1[j]]};
        Q3p[j] = (v2){kQ3[pr0[j]], kQ3[pr1[j]]};
        BWp[j] = (v2){kBW[pr0[j]], kBW[pr1[j]]};
    }

    // ---- per-element state (x2): hidden pairs + inputs
    const int EE[2] = { eA, eB };
    v2 H04[2], H12[2], H36[2];
    float H5[2];
    long BASE[2];
    float4 XC[2];
    const float4* inp4 = (const float4*)inputs;
#pragma unroll
    for (int j = 0; j < 2; ++j) {
        const int e = EE[j];
        H04[j] = (v2){REVC*initial_t[e*7+0], REVC*initial_t[e*7+4]};
        H12[j] = (v2){REVC*initial_t[e*7+1], REVC*initial_t[e*7+2]};
        H36[j] = (v2){REVC*initial_t[e*7+3], REVC*initial_t[e*7+6]};
        H5[j]  = REVC*initial_t[e*7+5];
        BASE[j] = (long)e * S;
        XC[j] = inp4[BASE[j]];
    }

    const float NQPI = -0.7853981633974483f;   // -pi/4
    float XK[2] = {0.f, 0.f};
    v2 A0[2], A1[2];

#pragma unroll 1
    for (int t = 0; t < S; ++t) {
        const int tn = (t + 1 < S) ? t + 1 : S - 1;
        float4 XN[2];
#pragma unroll
        for (int j = 0; j < 2; ++j) XN[j] = inp4[BASE[j] + tn];

        // ---- fm(hidden) on |0000>: amp = e^{i*2pi*sig}
#pragma unroll
        for (int j = 0; j < 2; ++j) {
            float base = H12[j].x * z1f;
            base = fmaf(H12[j].y, z2f, base);
            base = fmaf(H36[j].x, z3f, base);
            base = fmaf(H5[j],   z12, base);
            base = fmaf(H36[j].y, z23, base);
            float w = fmaf(H04[j].y, z1f, H04[j].x);
            float s0, c0, s1, c1;
            fsincos(base + w, &s0, &c0);
            fsincos(base - w, &s1, &c1);
            A0[j] = (v2){c0, s0};
            A1[j] = (v2){c1, s1};
        }

        // ---- ansatz(p1), fm(x), ansatz(p2). Layer-2 CNOT(3,0) folded into
        // fm_x; layer-4 ring folded into measurement Walsh masks.
#pragma unroll
        for (int half = 0; half < 2; ++half) {
#pragma unroll
            for (int li = 0; li < 2; ++li) {
                const int l = half*2 + li;
#pragma unroll
                for (int j = 0; j < 2; ++j)
                    rot_q0v(A0[j], A1[j], Sr[l], Tr[l], nTr[l], Sin[l], Tin[l]);
#pragma unroll
                for (int j = 0; j < 2; ++j) {  // qubit1
                    v2 q0 = qpermv<0x128>(A0[j]), q1 = qpermv<0x128>(A1[j]);
                    A0[j] = rot_dv(A0[j], q0, Ur[l][0], An[l][0], Br[l][0], Wn[l][0]);
                    A1[j] = rot_dv(A1[j], q1, Ur[l][0], An[l][0], Br[l][0], Wn[l][0]);
                }
#pragma unroll
                for (int j = 0; j < 2; ++j) {  // qubit2
                    v2 q0 = qpermv<0xB1>(A0[j]), q1 = qpermv<0xB1>(A1[j]);
                    A0[j] = rot_dv(A0[j], q0, Ur[l][1], An[l][1], Br[l][1], Wn[l][1]);
                    A1[j] = rot_dv(A1[j], q1, Ur[l][1], An[l][1], Br[l][1], Wn[l][1]);
                }
#pragma unroll
                for (int j = 0; j < 2; ++j) {  // qubit3
                    v2 q0 = qpermv<0x4E>(A0[j]), q1 = qpermv<0x4E>(A1[j]);
                    A0[j] = rot_dv(A0[j], q0, Ur[l][2], An[l][2], Br[l][2], Wn[l][2]);
                    A1[j] = rot_dv(A1[j], q1, Ur[l][2], An[l][2], Br[l][2], Wn[l][2]);
                }
                if (l < 3) {
#pragma unroll
                    for (int j = 0; j < 2; ++j) {
                        // CNOT(0,1)
                        A1[j] = qpermv<0x128>(A1[j]);
                        // CNOT(1,2) o CNOT(2,3): b1=0 -> [0,3,2,1]; b1=1 -> [1,2,3,0]
                        float vA, vB;
                        vA = qperm<0x6C>(A0[j].x); vB = qperm<0x39>(A0[j].x); A0[j].x = b1 ? vB : vA;
                        vA = qperm<0x6C>(A0[j].y); vB = qperm<0x39>(A0[j].y); A0[j].y = b1 ? vB : vA;
                        vA = qperm<0x6C>(A1[j].x); vB = qperm<0x39>(A1[j].x); A1[j].x = b1 ? vB : vA;
                        vA = qperm<0x6C>(A1[j].y); vB = qperm<0x39>(A1[j].y); A1[j].y = b1 ? vB : vA;
                        // CNOT(3,0): layers 1,3 only (layer 2's folded into fm_x)
                        if (li == 0) {
                            v2 t0 = b3 ? A1[j] : A0[j];
                            v2 t1 = b3 ? A0[j] : A1[j];
                            A0[j] = t0; A1[j] = t1;
                        }
                    }
                }
            }
            if (half == 0) {
                // ---- fm(x_embed): H^{x4} (unscaled) + diag phase (revolutions)
#pragma unroll
                for (int j = 0; j < 2; ++j) {
                    float hx0 = REVC*XC[j].x, hx1 = REVC*XC[j].y;
                    float hx2 = REVC*XC[j].z, hx3 = REVC*XC[j].w;
                    float u0 = fmaf(4.f, hx0, 1.f);
                    float u1 = fmaf(4.f, hx1, 1.f);
                    float u2 = fmaf(4.f, hx2, 1.f);
                    float u3 = fmaf(4.f, hx3, 1.f);
                    float he4 = NQPI * (u0*u1);
                    float he5 = NQPI * (u1*u2);
                    float he6 = NQPI * (u2*u3);

                    // H q0 + folded layer-2 CNOT(3,0): diff scaled by z3f
                    v2 n0 = A0[j] + A1[j];
                    v2 n1 = (A0[j] - A1[j]) * z3f;
                    A0[j] = n0; A1[j] = n1;
                    { v2 q0 = qpermv<0x128>(A0[j]), q1 = qpermv<0x128>(A1[j]);
                      A0[j] = vfma(A0[j], vsplat(z1f), q0);
                      A1[j] = vfma(A1[j], vsplat(z1f), q1); }
                    { v2 q0 = qpermv<0xB1>(A0[j]), q1 = qpermv<0xB1>(A1[j]);
                      A0[j] = vfma(A0[j], vsplat(z2f), q0);
                      A1[j] = vfma(A1[j], vsplat(z2f), q1); }
                    { v2 q0 = qpermv<0x4E>(A0[j]), q1 = qpermv<0x4E>(A1[j]);
                      A0[j] = vfma(A0[j], vsplat(z3f), q0);
                      A1[j] = vfma(A1[j], vsplat(z3f), q1); }
                    float base = hx1 * z1f;
                    base = fmaf(hx2, z2f, base);
                    base = fmaf(hx3, z3f, base);
                    base = fmaf(he5, z12, base);
                    base = fmaf(he6, z23, base);
                    float w = fmaf(he4, z1f, hx0);
                    float s0, c0, s1, c1;
                    fsincos(base + w, &s0, &c0);
                    fsincos(base - w, &s1, &c1);
                    v2 sn0 = (v2){-s0, s0};
                    v2 sn1 = (v2){-s1, s1};
                    A0[j] = vfma(vswap(A0[j]), sn0, A0[j] * c0);
                    A1[j] = vfma(vswap(A1[j]), sn1, A1[j] * c1);
                }
            }
        }

        // ---- measurement (layer-4 ring folded into Walsh masks; probs x256)
#pragma unroll
        for (int j = 0; j < 2; ++j) {
            v2 m0 = A0[j] * A0[j], m1 = A1[j] * A1[j];
            float pa = m0.x + m0.y;
            float pb = m1.x + m1.y;
            float s  = pa + pb;
            float dl = pa - pb;
            float u0m = z1f * dl;
            float r3 = u0m + ror8(u0m);
            float rA = r3 + lx1(r3); rA += lx2(rA);       // ev1 everywhere
            float rB = r3 - lx1(r3);
            float rC = fmaf(z2f, lx2(rB), rB);            // sub2->ev2, sub3->ev3
            float vy = z123 * s;
            vy += ror8(vy); vy += lx1(vy); vy += lx2(vy); // ev0 everywhere
            float pre = is0 ? vy : (is1 ? rA : rC);
            XK[j] = pre * (1.0f/256.0f);
        }

        // ---- KAN (packed pairs): lane sub = input dim; quad-reduce sums dims
#pragma unroll
        for (int j = 0; j < 2; ++j) {
            float xk = XK[j];
            float eneg = __builtin_amdgcn_exp2f(xk * -1.44269504088896f);
            float silu = xk * __builtin_amdgcn_rcpf(1.0f + eneg);
            v2 xs = vsplat(xk), ss = vsplat(silu);
            v2 op[3];
#pragma unroll
            for (int k = 0; k < 3; ++k) {
                v2 o = vfma(Q3p[k], xs, Q2p[k]);
                o = vfma(o, xs, Q1p[k]);
                o = vfma(o, xs, Q0p[k]);
                o = vfma(BWp[k], ss, o);
                o = o + (v2){lx1(o.x), lx1(o.y)};
                o = o + (v2){lx2(o.x), lx2(o.y)};
                op[k] = o;
            }
            {   // scalar r=5
                float o = fmaf(kQ3[5], xk, kQ2[5]);
                o = fmaf(o, xk, kQ1[5]);
                o = fmaf(o, xk, kQ0[5]);
                o = fmaf(kBW[5], silu, o);
                o += lx1(o); o += lx2(o);
                H5[j] = o;
            }
            H04[j] = op[0]; H12[j] = op[1]; H36[j] = op[2];
            XC[j] = XN[j];
        }
    }

    // ---- classifier head: quad lanes hold ev0..ev3 per element
#pragma unroll
    for (int j = 0; j < 2; ++j) {
        float xk  = XK[j];
        float ev1 = qperm<0x55>(xk);
        float ev2 = qperm<0xAA>(xk);
        float ev3 = qperm<0xFF>(xk);
        if (sub == 0 && !b1) {
            float acc = cb2[0];
#pragma unroll
            for (int i = 0; i < 16; ++i) {
                float h = cb1[i] + w1[i*4+0]*xk + w1[i*4+1]*ev1
                        + w1[i*4+2]*ev2 + w1[i*4+3]*ev3;
                h = fmaxf(h, 0.0f);
                acc += w2[i]*h;
            }
            out[EE[j]] = acc;
        }
    }
}

extern "C" void kernel_launch(void* const* d_in, const int* in_sizes, int n_in,
                              void* d_out, int out_size, void* d_ws, size_t ws_size,
                              hipStream_t stream) {
    const float* inputs    = (const float*)d_in[0];
    const float* initial_t = (const float*)d_in[1];
    const float* p1        = (const float*)d_in[2];
    const float* p2        = (const float*)d_in[3];
    const float* kbw       = (const float*)d_in[4];
    const float* ksw       = (const float*)d_in[5];
    const float* w1        = (const float*)d_in[6];
    const float* cb1       = (const float*)d_in[7];
    const float* w2        = (const float*)d_in[8];
    const float* cb2       = (const float*)d_in[9];

    const int B = in_sizes[1] / 7;            // 16384
    const int S = in_sizes[0] / (B * 4);      // 256

    const int threads = (B / 2) * 8;          // 8 lanes/slot, 2 elements/thread
    const int block = 256;
    const int grid = (threads + block - 1) / block;   // 256 blocks -> 1 wave/SIMD

    qrnn_kernel<<<grid, block, 0, stream>>>(inputs, initial_t, p1, p2, kbw, ksw,
                                            w1, cb1, w2, cb2, (float*)d_out, B, S);
}